// Round 1
// 1479.953 us; speedup vs baseline: 1.1981x; 1.1981x over previous
//
#include <hip/hip_runtime.h>
#include <hip/hip_bf16.h>
#include <math.h>

#define B_   2
#define S_   1024
#define D_   1024
#define H_   16
#define HD_  64
#define NL_  6
#define DFF_ 4096

typedef __bf16 bf16_t;
typedef bf16_t bf16x8 __attribute__((ext_vector_type(8)));
typedef bf16_t bf16x4 __attribute__((ext_vector_type(4)));
typedef float  f32x4  __attribute__((ext_vector_type(4)));

__device__ __forceinline__ float gelu_exact(float x) {
    return 0.5f * x * (1.0f + erff(x * 0.70710678118654752f));
}

// ---------------- y = x + pos (pos broadcast over batch); fp32 + bf16 out ----------------
__global__ __launch_bounds__(256) void add_pos_kernel(
    const float* __restrict__ x, const float* __restrict__ pos,
    float* __restrict__ y, bf16_t* __restrict__ yb)
{
    int idx = blockIdx.x * 256 + threadIdx.x;      // float4 index, [0, 524288)
    f32x4 xv = *(const f32x4*)&x[idx * 4];
    f32x4 pv = *(const f32x4*)&pos[(idx & 262143) * 4];  // S*D/4 = 262144
    f32x4 o = xv + pv;
    *(f32x4*)&y[idx * 4] = o;
    *(bf16x4*)&yb[idx * 4] = __builtin_convertvector(o, bf16x4);
}

// ---------------- QKV projection via MFMA ----------------
// yb viewed as (B*S*H, 64); q/k/v = yb @ W{q,k,v}(64x64) + b (weights shared over heads).
// grid 256 blocks x 256 thr (4 waves); block tile M=128, N=64, K=64; wave tile 32x64.
__global__ __launch_bounds__(256) void qkv_mfma_kernel(
    const bf16_t* __restrict__ yb,
    const float* __restrict__ Wq, const float* __restrict__ bq,
    const float* __restrict__ Wk, const float* __restrict__ bk,
    const float* __restrict__ Wv, const float* __restrict__ bv,
    bf16_t* __restrict__ q, bf16_t* __restrict__ k, bf16_t* __restrict__ v)
{
    __shared__ bf16_t As[128][72];
    __shared__ bf16_t Wt[3][64][72];   // W^T: [n][k], bf16

    int tid = threadIdx.x;
    long m0 = (long)blockIdx.x * 128;

#pragma unroll
    for (int it = 0; it < 4; ++it) {
        int c = it * 256 + tid;            // [0,1024) x8 elems
        int row = c >> 3, col = (c & 7) * 8;
        *(bf16x8*)&As[row][col] = *(const bf16x8*)&yb[(m0 + row) * 64 + col];
    }
#pragma unroll
    for (int it = 0; it < 16; ++it) {
        int i = it * 256 + tid;            // [0,4096)
        int r = i >> 6, c = i & 63;
        Wt[0][c][r] = (bf16_t)Wq[i];
        Wt[1][c][r] = (bf16_t)Wk[i];
        Wt[2][c][r] = (bf16_t)Wv[i];
    }
    __syncthreads();

    int wave = tid >> 6, lane = tid & 63;
    int quad = lane >> 4, l16 = lane & 15;
    int wm = wave * 32;

    bf16x8 a[2][2];
#pragma unroll
    for (int i = 0; i < 2; ++i)
#pragma unroll
        for (int ks = 0; ks < 2; ++ks)
            a[i][ks] = *(bf16x8*)&As[wm + i * 16 + l16][ks * 32 + quad * 8];

    f32x4 acc[3][2][4];
#pragma unroll
    for (int o = 0; o < 3; ++o)
#pragma unroll
        for (int i = 0; i < 2; ++i)
#pragma unroll
            for (int j = 0; j < 4; ++j) acc[o][i][j] = (f32x4)0.f;

#pragma unroll
    for (int o = 0; o < 3; ++o)
#pragma unroll
        for (int j = 0; j < 4; ++j) {
            bf16x8 b0 = *(bf16x8*)&Wt[o][j * 16 + l16][quad * 8];
            bf16x8 b1 = *(bf16x8*)&Wt[o][j * 16 + l16][32 + quad * 8];
#pragma unroll
            for (int i = 0; i < 2; ++i) {
                acc[o][i][j] = __builtin_amdgcn_mfma_f32_16x16x32_bf16(a[i][0], b0, acc[o][i][j], 0, 0, 0);
                acc[o][i][j] = __builtin_amdgcn_mfma_f32_16x16x32_bf16(a[i][1], b1, acc[o][i][j], 0, 0, 0);
            }
        }

    bf16_t* outs[3] = { q, k, v };
    const float* biases[3] = { bq, bk, bv };
#pragma unroll
    for (int o = 0; o < 3; ++o)
#pragma unroll
        for (int j = 0; j < 4; ++j) {
            int col = j * 16 + l16;
            float bias = biases[o][col];
#pragma unroll
            for (int i = 0; i < 2; ++i) {
                long rbase = m0 + wm + i * 16 + quad * 4;
#pragma unroll
                for (int r = 0; r < 4; ++r)
                    outs[o][(rbase + r) * 64 + col] = (bf16_t)(acc[o][i][j][r] + bias);
            }
        }
}

// ---------------- causal flash attention, bf16 MFMA, 64q x 32kv tiles ----------------
__global__ __launch_bounds__(256) void attn_mfma_kernel(
    const bf16_t* __restrict__ Q, const bf16_t* __restrict__ K,
    const bf16_t* __restrict__ V, bf16_t* __restrict__ Ob)
{
    __shared__ bf16_t Ks[32][72];       // [kv][d], pad 8
    __shared__ bf16_t Vt[64][40];       // [d][kv], pad 8
    __shared__ bf16_t Ps[4][16][40];    // per-wave P tile [q][kv], pad 8

    int tid = threadIdx.x;
    int wave = tid >> 6, lane = tid & 63;
    int quad = lane >> 4, l16 = lane & 15;
    int q0 = blockIdx.x * 64;
    int bh = blockIdx.y;
    int b = bh >> 4, h = bh & 15;
    int qw = q0 + wave * 16;
    const float scale = 0.125f;             // 1/sqrt(64)
    const float MASKED = -1.25e19f;         // -1e20 * scale, per reference order

    const bf16_t* Qbase = Q + (((long)b * S_ + qw + l16) * H_ + h) * HD_;
    bf16x8 aq0 = *(const bf16x8*)&Qbase[quad * 8];
    bf16x8 aq1 = *(const bf16x8*)&Qbase[32 + quad * 8];

    float mrun[4], lrun[4];
    f32x4 oacc[4];
#pragma unroll
    for (int r = 0; r < 4; ++r) { mrun[r] = -3.0e38f; lrun[r] = 0.f; }
#pragma unroll
    for (int n = 0; n < 4; ++n) oacc[n] = (f32x4)0.f;

    int srow = tid >> 3, scol = (tid & 7) * 8;   // staging: 32 rows x 64 d
    int nkt = (q0 + 64) / 32;
    for (int kt = 0; kt < nkt; ++kt) {
        int k0 = kt * 32;
        __syncthreads();
        {
            long base = (((long)b * S_ + k0 + srow) * H_ + h) * HD_ + scol;
            *(bf16x8*)&Ks[srow][scol] = *(const bf16x8*)&K[base];
            bf16x8 vv = *(const bf16x8*)&V[base];
#pragma unroll
            for (int j = 0; j < 8; ++j) Vt[scol + j][srow] = vv[j];
        }
        __syncthreads();

        f32x4 sc[2];
        sc[0] = (f32x4)0.f; sc[1] = (f32x4)0.f;
#pragma unroll
        for (int n = 0; n < 2; ++n) {
            bf16x8 bk0 = *(bf16x8*)&Ks[n * 16 + l16][quad * 8];
            bf16x8 bk1 = *(bf16x8*)&Ks[n * 16 + l16][32 + quad * 8];
            sc[n] = __builtin_amdgcn_mfma_f32_16x16x32_bf16(aq0, bk0, sc[n], 0, 0, 0);
            sc[n] = __builtin_amdgcn_mfma_f32_16x16x32_bf16(aq1, bk1, sc[n], 0, 0, 0);
        }

        float alpha[4];
#pragma unroll
        for (int r = 0; r < 4; ++r) {
            int qg = qw + quad * 4 + r;
            float s0 = (k0 + l16      <= qg) ? sc[0][r] * scale : MASKED;
            float s1 = (k0 + 16 + l16 <= qg) ? sc[1][r] * scale : MASKED;
            float mt = fmaxf(s0, s1);
            mt = fmaxf(mt, __shfl_xor(mt, 1));
            mt = fmaxf(mt, __shfl_xor(mt, 2));
            mt = fmaxf(mt, __shfl_xor(mt, 4));
            mt = fmaxf(mt, __shfl_xor(mt, 8));
            float mnew = fmaxf(mrun[r], mt);
            float p0 = __expf(s0 - mnew);
            float p1 = __expf(s1 - mnew);
            float ls = p0 + p1;
            ls += __shfl_xor(ls, 1);
            ls += __shfl_xor(ls, 2);
            ls += __shfl_xor(ls, 4);
            ls += __shfl_xor(ls, 8);
            alpha[r] = __expf(mrun[r] - mnew);
            lrun[r] = lrun[r] * alpha[r] + ls;
            mrun[r] = mnew;
            int prow = quad * 4 + r;
            Ps[wave][prow][l16]      = (bf16_t)p0;
            Ps[wave][prow][16 + l16] = (bf16_t)p1;
        }
        bf16x8 ap = *(bf16x8*)&Ps[wave][l16][quad * 8];

#pragma unroll
        for (int n = 0; n < 4; ++n) {
            bf16x8 bv = *(bf16x8*)&Vt[n * 16 + l16][quad * 8];
            f32x4 c = oacc[n];
#pragma unroll
            for (int r = 0; r < 4; ++r) c[r] *= alpha[r];
            oacc[n] = __builtin_amdgcn_mfma_f32_16x16x32_bf16(ap, bv, c, 0, 0, 0);
        }
    }

#pragma unroll
    for (int r = 0; r < 4; ++r) {
        float inv = 1.0f / lrun[r];
        long rowbase = (((long)b * S_ + qw + quad * 4 + r) * H_ + h) * HD_;
#pragma unroll
        for (int n = 0; n < 4; ++n)
            Ob[rowbase + n * 16 + l16] = (bf16_t)(oacc[n][r] * inv);
    }
}

// ---------------- transpose + fp32->bf16 convert: W[Kd x Nd] -> Wt[Nd x Kd] ----------------
__global__ void tconv_kernel(const float* __restrict__ W, bf16_t* __restrict__ Wt,
                             int Kd, int Nd)
{
    __shared__ float t[32][33];
    int tx = threadIdx.x, ty = threadIdx.y;  // (32, 8)
    int bx = blockIdx.x, by = blockIdx.y;
#pragma unroll
    for (int i = 0; i < 4; ++i)
        t[ty + i * 8][tx] = W[(size_t)(by * 32 + ty + i * 8) * Nd + bx * 32 + tx];
    __syncthreads();
#pragma unroll
    for (int i = 0; i < 4; ++i)
        Wt[(size_t)(bx * 32 + ty + i * 8) * Kd + by * 32 + tx] = (bf16_t)t[tx][ty + i * 8];
}

// ---------------- bf16 MFMA GEMM: C[MxN] = A[MxK] * Bt[NxK]^T + bias ----------------
// BM=128 fixed, BN templated (128 or 64). 4 waves; wave tile 64 x (BN/2).
// grid.z = K-split count; split z writes fp32 partial to Cf + z*pstride,
// bias added only in split 0 (the downstream ln_fused sums the partials).
#define LDT 40
template<int BN>
__global__ __launch_bounds__(256) void gemm_bt_kernel(
    const bf16_t* __restrict__ A, const bf16_t* __restrict__ Bt,
    const float* __restrict__ bias, float* __restrict__ Cf,
    bf16_t* __restrict__ Cb, int M, int N, int K, int act, size_t pstride)
{
    __shared__ bf16_t As[128 * LDT];
    __shared__ bf16_t Bs[BN * LDT];
    int tid = threadIdx.x;
    int wave = tid >> 6, lane = tid & 63;
    int quad = lane >> 4, l16 = lane & 15;
    int m0 = blockIdx.x * 128;
    int n0 = blockIdx.y * BN;
    int Kc = K / gridDim.z;
    int kbeg = blockIdx.z * Kc;
    int kend = kbeg + Kc;
    float* Cfp = Cf ? Cf + (size_t)blockIdx.z * pstride : nullptr;

    constexpr int WN = BN / 2;       // wave tile N
    constexpr int NJ = WN / 16;      // 4 for BN=128, 2 for BN=64
    int wm = (wave >> 1) * 64, wn = (wave & 1) * WN;

    f32x4 acc[4][NJ];
#pragma unroll
    for (int i = 0; i < 4; ++i)
#pragma unroll
        for (int j = 0; j < NJ; ++j) acc[i][j] = (f32x4)0.f;

    for (int k0 = kbeg; k0 < kend; k0 += 32) {
        __syncthreads();
#pragma unroll
        for (int it = 0; it < 2; ++it) {
            int c = it * 256 + tid;          // [0,512)
            int row = c >> 2, col = (c & 3) * 8;
            *(bf16x8*)&As[row * LDT + col] =
                *(const bf16x8*)&A[(size_t)(m0 + row) * K + k0 + col];
        }
#pragma unroll
        for (int it = 0; it < BN / 64; ++it) {
            int c = it * 256 + tid;          // [0, BN*4)
            int row = c >> 2, col = (c & 3) * 8;
            *(bf16x8*)&Bs[row * LDT + col] =
                *(const bf16x8*)&Bt[(size_t)(n0 + row) * K + k0 + col];
        }
        __syncthreads();

        bf16x8 af[4], bfr[NJ];
#pragma unroll
        for (int i = 0; i < 4; ++i)
            af[i] = *(bf16x8*)&As[(wm + i * 16 + l16) * LDT + quad * 8];
#pragma unroll
        for (int j = 0; j < NJ; ++j)
            bfr[j] = *(bf16x8*)&Bs[(wn + j * 16 + l16) * LDT + quad * 8];
#pragma unroll
        for (int i = 0; i < 4; ++i)
#pragma unroll
            for (int j = 0; j < NJ; ++j)
                acc[i][j] = __builtin_amdgcn_mfma_f32_16x16x32_bf16(
                    af[i], bfr[j], acc[i][j], 0, 0, 0);
    }

#pragma unroll
    for (int j = 0; j < NJ; ++j) {
        int col = n0 + wn + j * 16 + l16;
        float bv = (bias && blockIdx.z == 0) ? bias[col] : 0.f;
#pragma unroll
        for (int i = 0; i < 4; ++i) {
            int rbase = m0 + wm + i * 16 + quad * 4;
#pragma unroll
            for (int r = 0; r < 4; ++r) {
                float vv = acc[i][j][r] + bv;
                if (act == 1) vv = gelu_exact(vv);
                if (Cfp) Cfp[(size_t)(rbase + r) * N + col] = vv;
                if (Cb) Cb[(size_t)(rbase + r) * N + col] = (bf16_t)vv;
            }
        }
    }
}

// ---------------- fused (partial-sum) residual add + LayerNorm (row = one block) ----------------
// z = a0 + a1(opt) + b(opt); out may alias a1 (row-wise read-before-write).
__global__ __launch_bounds__(256) void ln_fused_kernel(
    const float* __restrict__ a0, const float* __restrict__ a1,
    const float* __restrict__ b,
    const float* __restrict__ w, const float* __restrict__ beta,
    float* __restrict__ out, bf16_t* __restrict__ outb)
{
    long row = blockIdx.x;
    int tid = threadIdx.x;
    f32x4 z = *(const f32x4*)&a0[row * D_ + tid * 4];
    if (a1) z += *(const f32x4*)&a1[row * D_ + tid * 4];
    if (b)  z += *(const f32x4*)&b[row * D_ + tid * 4];
    float s  = z[0] + z[1] + z[2] + z[3];
    float ss = z[0]*z[0] + z[1]*z[1] + z[2]*z[2] + z[3]*z[3];
#pragma unroll
    for (int off = 32; off >= 1; off >>= 1) {
        s  += __shfl_down(s, off);
        ss += __shfl_down(ss, off);
    }
    __shared__ float red[8];
    int lane = tid & 63, wid = tid >> 6;
    if (lane == 0) { red[wid * 2] = s; red[wid * 2 + 1] = ss; }
    __syncthreads();
    s  = red[0] + red[2] + red[4] + red[6];
    ss = red[1] + red[3] + red[5] + red[7];
    float mean = s * (1.0f / D_);
    float var  = ss * (1.0f / D_) - mean * mean;
    float rs = rsqrtf(var + 1e-5f);
    f32x4 wv = *(const f32x4*)&w[tid * 4];
    f32x4 bv = *(const f32x4*)&beta[tid * 4];
    f32x4 o = (z - mean) * rs * wv + bv;
    *(f32x4*)&out[row * D_ + tid * 4] = o;
    if (outb) *(bf16x4*)&outb[row * D_ + tid * 4] = __builtin_convertvector(o, bf16x4);
}

// ---------------- host launch ----------------
extern "C" void kernel_launch(void* const* d_in, const int* in_sizes, int n_in,
                              void* d_out, int out_size, void* d_ws, size_t ws_size,
                              hipStream_t stream)
{
    (void)in_sizes; (void)n_in; (void)out_size; (void)ws_size;
    const float* x    = (const float*)d_in[0];
    const float* pos  = (const float*)d_in[1];
    const float* Wq   = (const float*)d_in[2];
    const float* bq   = (const float*)d_in[3];
    const float* Wk   = (const float*)d_in[4];
    const float* bk   = (const float*)d_in[5];
    const float* Wv   = (const float*)d_in[6];
    const float* bv   = (const float*)d_in[7];
    const float* Wfc  = (const float*)d_in[8];
    const float* bfc  = (const float*)d_in[9];
    const float* ln1w = (const float*)d_in[10];
    const float* ln1b = (const float*)d_in[11];
    const float* ln2w = (const float*)d_in[12];
    const float* ln2b = (const float*)d_in[13];
    const float* W1   = (const float*)d_in[14];
    const float* b1   = (const float*)d_in[15];
    const float* W2   = (const float*)d_in[16];
    const float* b2   = (const float*)d_in[17];
    const float* lnfw = (const float*)d_in[18];
    const float* lnfb = (const float*)d_in[19];

    const size_t MB = 1 << 20;
    char* ws = (char*)d_ws;
    float*  y    = (float*)(ws);             //  0-8   fp32 activations
    bf16_t* yb   = (bf16_t*)(ws + 8 * MB);   //  8-12  bf16 activations
    bf16_t* qb   = (bf16_t*)(ws + 12 * MB);  // 12-16
    bf16_t* kb   = (bf16_t*)(ws + 16 * MB);  // 16-20
    bf16_t* vb   = (bf16_t*)(ws + 20 * MB);  // 20-24
    bf16_t* ob   = (bf16_t*)(ws + 24 * MB);  // 24-28
    float*  t1a  = (float*)(ws + 12 * MB);   // 12-20  Wfc partial 0 (qb/kb dead after attn)
    float*  t1b  = (float*)(ws + 28 * MB);   // 28-36  Wfc partial 1 (aliases 'add'; ln1 reduces in place)
    float*  t2a  = (float*)(ws + 12 * MB);   // 12-20  FFN2 partial 0
    float*  t2b  = (float*)(ws + 20 * MB);   // 20-28  FFN2 partial 1 (vb/ob dead by then)
    float*  add  = (float*)(ws + 28 * MB);   // 28-36
    bf16_t* addb = (bf16_t*)(ws + 36 * MB);  // 36-40
    bf16_t* ffb  = (bf16_t*)(ws + 40 * MB);  // 40-56
    bf16_t* WT   = (bf16_t*)(ws + 56 * MB);  // 56-64  per-layer weight transpose

    const size_t pstride_wfc  = (size_t)16 * MB / sizeof(float); // t1b - t1a
    const size_t pstride_ffn2 = (size_t)8 * MB / sizeof(float);  // t2b - t2a

    add_pos_kernel<<<2048, 256, 0, stream>>>(x, pos, y, yb);

    for (int i = 0; i < NL_; ++i) {
        qkv_mfma_kernel<<<256, 256, 0, stream>>>(
            yb, Wq + i * 4096, bq + i * 64, Wk + i * 4096, bk + i * 64,
            Wv + i * 4096, bv + i * 64, qb, kb, vb);

        attn_mfma_kernel<<<dim3(16, 32), 256, 0, stream>>>(qb, kb, vb, ob);

        // ---- attention output projection: split-K=2, BN=64 -> 512 blocks ----
        tconv_kernel<<<dim3(32, 32), dim3(32, 8), 0, stream>>>(
            Wfc + (size_t)i * D_ * D_, WT, D_, D_);
        gemm_bt_kernel<64><<<dim3(16, 16, 2), 256, 0, stream>>>(
            ob, WT, bfc + i * D_, t1a, nullptr, 2048, D_, D_, 0, pstride_wfc);

        ln_fused_kernel<<<2048, 256, 0, stream>>>(
            t1a, t1b, y, ln1w + i * D_, ln1b + i * D_, add, addb);

        // ---- FFN1: 512 blocks already, unchanged ----
        tconv_kernel<<<dim3(128, 32), dim3(32, 8), 0, stream>>>(
            W1 + (size_t)i * D_ * DFF_, WT, D_, DFF_);
        gemm_bt_kernel<128><<<dim3(16, 32, 1), 256, 0, stream>>>(
            addb, WT, b1 + i * DFF_, nullptr, ffb, 2048, DFF_, D_, 1, 0);

        // ---- FFN2: split-K=2, BN=64 -> 512 blocks ----
        tconv_kernel<<<dim3(32, 128), dim3(32, 8), 0, stream>>>(
            W2 + (size_t)i * DFF_ * D_, WT, DFF_, D_);
        gemm_bt_kernel<64><<<dim3(16, 16, 2), 256, 0, stream>>>(
            ffb, WT, b2 + i * D_, t2a, nullptr, 2048, D_, DFF_, 0, pstride_ffn2);

        ln_fused_kernel<<<2048, 256, 0, stream>>>(
            t2a, t2b, add, ln2w + i * D_, ln2b + i * D_, y, yb);
    }

    ln_fused_kernel<<<2048, 256, 0, stream>>>(
        y, nullptr, nullptr, lnfw, lnfb, (float*)d_out, nullptr);
}

// Round 2
// 1353.578 us; speedup vs baseline: 1.3099x; 1.0934x over previous
//
#include <hip/hip_runtime.h>
#include <hip/hip_bf16.h>
#include <math.h>

#define B_   2
#define S_   1024
#define D_   1024
#define H_   16
#define HD_  64
#define NL_  6
#define DFF_ 4096

typedef __bf16 bf16_t;
typedef bf16_t bf16x8 __attribute__((ext_vector_type(8)));
typedef bf16_t bf16x4 __attribute__((ext_vector_type(4)));
typedef float  f32x4  __attribute__((ext_vector_type(4)));

__device__ __forceinline__ float gelu_exact(float x) {
    return 0.5f * x * (1.0f + erff(x * 0.70710678118654752f));
}

// ---------------- y = x + pos (pos broadcast over batch); fp32 + bf16 out ----------------
__global__ __launch_bounds__(256) void add_pos_kernel(
    const float* __restrict__ x, const float* __restrict__ pos,
    float* __restrict__ y, bf16_t* __restrict__ yb)
{
    int idx = blockIdx.x * 256 + threadIdx.x;      // float4 index, [0, 524288)
    f32x4 xv = *(const f32x4*)&x[idx * 4];
    f32x4 pv = *(const f32x4*)&pos[(idx & 262143) * 4];  // S*D/4 = 262144
    f32x4 o = xv + pv;
    *(f32x4*)&y[idx * 4] = o;
    *(bf16x4*)&yb[idx * 4] = __builtin_convertvector(o, bf16x4);
}

// ---------------- QKV projection via MFMA ----------------
__global__ __launch_bounds__(256) void qkv_mfma_kernel(
    const bf16_t* __restrict__ yb,
    const float* __restrict__ Wq, const float* __restrict__ bq,
    const float* __restrict__ Wk, const float* __restrict__ bk,
    const float* __restrict__ Wv, const float* __restrict__ bv,
    bf16_t* __restrict__ q, bf16_t* __restrict__ k, bf16_t* __restrict__ v)
{
    __shared__ bf16_t As[128][72];
    __shared__ bf16_t Wt[3][64][72];   // W^T: [n][k], bf16

    int tid = threadIdx.x;
    long m0 = (long)blockIdx.x * 128;

#pragma unroll
    for (int it = 0; it < 4; ++it) {
        int c = it * 256 + tid;            // [0,1024) x8 elems
        int row = c >> 3, col = (c & 7) * 8;
        *(bf16x8*)&As[row][col] = *(const bf16x8*)&yb[(m0 + row) * 64 + col];
    }
#pragma unroll
    for (int it = 0; it < 16; ++it) {
        int i = it * 256 + tid;            // [0,4096)
        int r = i >> 6, c = i & 63;
        Wt[0][c][r] = (bf16_t)Wq[i];
        Wt[1][c][r] = (bf16_t)Wk[i];
        Wt[2][c][r] = (bf16_t)Wv[i];
    }
    __syncthreads();

    int wave = tid >> 6, lane = tid & 63;
    int quad = lane >> 4, l16 = lane & 15;
    int wm = wave * 32;

    bf16x8 a[2][2];
#pragma unroll
    for (int i = 0; i < 2; ++i)
#pragma unroll
        for (int ks = 0; ks < 2; ++ks)
            a[i][ks] = *(bf16x8*)&As[wm + i * 16 + l16][ks * 32 + quad * 8];

    f32x4 acc[3][2][4];
#pragma unroll
    for (int o = 0; o < 3; ++o)
#pragma unroll
        for (int i = 0; i < 2; ++i)
#pragma unroll
            for (int j = 0; j < 4; ++j) acc[o][i][j] = (f32x4)0.f;

#pragma unroll
    for (int o = 0; o < 3; ++o)
#pragma unroll
        for (int j = 0; j < 4; ++j) {
            bf16x8 b0 = *(bf16x8*)&Wt[o][j * 16 + l16][quad * 8];
            bf16x8 b1 = *(bf16x8*)&Wt[o][j * 16 + l16][32 + quad * 8];
#pragma unroll
            for (int i = 0; i < 2; ++i) {
                acc[o][i][j] = __builtin_amdgcn_mfma_f32_16x16x32_bf16(a[i][0], b0, acc[o][i][j], 0, 0, 0);
                acc[o][i][j] = __builtin_amdgcn_mfma_f32_16x16x32_bf16(a[i][1], b1, acc[o][i][j], 0, 0, 0);
            }
        }

    bf16_t* outs[3] = { q, k, v };
    const float* biases[3] = { bq, bk, bv };
#pragma unroll
    for (int o = 0; o < 3; ++o)
#pragma unroll
        for (int j = 0; j < 4; ++j) {
            int col = j * 16 + l16;
            float bias = biases[o][col];
#pragma unroll
            for (int i = 0; i < 2; ++i) {
                long rbase = m0 + wm + i * 16 + quad * 4;
#pragma unroll
                for (int r = 0; r < 4; ++r)
                    outs[o][(rbase + r) * 64 + col] = (bf16_t)(acc[o][i][j][r] + bias);
            }
        }
}

// ---------------- V transpose: vb [b,s,h,d] -> vT [b,h,d,s] ----------------
__global__ __launch_bounds__(256) void vtrans_kernel(
    const bf16_t* __restrict__ vb, bf16_t* __restrict__ vT)
{
    __shared__ bf16_t L[32][72];
    int tid = threadIdx.x;
    int s0 = blockIdx.x * 32;
    int bh = blockIdx.y;
    int b = bh >> 4, h = bh & 15;
    int sr = tid >> 3, dc = (tid & 7) * 8;
    *(bf16x8*)&L[sr][dc] =
        *(const bf16x8*)&vb[(((long)b * S_ + s0 + sr) * H_ + h) * HD_ + dc];
    __syncthreads();
    int dr = tid >> 2, sg = (tid & 3) * 8;
    bf16x8 o;
#pragma unroll
    for (int j = 0; j < 8; ++j) o[j] = L[sg + j][dr];
    *(bf16x8*)&vT[((long)bh * HD_ + dr) * S_ + s0 + sg] = o;
}

// ---------------- causal flash attention, swapped-QK bf16 MFMA, 64q x 32kv ----------------
// sc = mfma(K,Q): score tile has q in lane-col (l16), kv in quad*4+r -> softmax
// reduction is register-local + 2 shfl_xor for all 16 q rows at once.
__global__ __launch_bounds__(256) void attn_mfma_kernel(
    const bf16_t* __restrict__ Q, const bf16_t* __restrict__ K,
    const bf16_t* __restrict__ VT, bf16_t* __restrict__ Ob)
{
    __shared__ bf16_t Ks[32][72];       // [kv][d]
    __shared__ bf16_t Vt[64][40];       // [d][kv]
    __shared__ bf16_t Ps[4][16][40];    // per-wave P tile [q][kv]

    int tid = threadIdx.x;
    int wave = tid >> 6, lane = tid & 63;
    int quad = lane >> 4, l16 = lane & 15;
    int q0 = blockIdx.x * 64;
    int bh = blockIdx.y;
    int b = bh >> 4, h = bh & 15;
    int qw = q0 + wave * 16;
    const float scale = 0.125f;             // 1/sqrt(64)
    const float MASKED = -1.25e19f;         // -1e20 * scale, per reference order

    const bf16_t* Qbase = Q + (((long)b * S_ + qw + l16) * H_ + h) * HD_;
    bf16x8 aq0 = *(const bf16x8*)&Qbase[quad * 8];        // B-frag: col=q(l16), k=d
    bf16x8 aq1 = *(const bf16x8*)&Qbase[32 + quad * 8];

    float mrun = -3.0e38f, lrun = 0.f;      // state for q = qw + l16 (replicated over quads)
    f32x4 oacc[4];
#pragma unroll
    for (int n = 0; n < 4; ++n) oacc[n] = (f32x4)0.f;

    int srow = tid >> 3, scol = (tid & 7) * 8;   // K staging: 32 kv x 64 d
    int vdr = tid >> 2, vkg = (tid & 3) * 8;     // V^T staging: 64 d x 32 kv
    const bf16_t* VTbase = VT + ((long)bh * HD_ + vdr) * S_ + vkg;
    int qg = qw + l16;

    int nkt = (q0 + 64) / 32;
    for (int kt = 0; kt < nkt; ++kt) {
        int k0 = kt * 32;
        __syncthreads();
        *(bf16x8*)&Ks[srow][scol] =
            *(const bf16x8*)&K[(((long)b * S_ + k0 + srow) * H_ + h) * HD_ + scol];
        *(bf16x8*)&Vt[vdr][vkg] = *(const bf16x8*)&VTbase[k0];
        __syncthreads();

        if (k0 > qw + 15) continue;          // fully-masked tile for this wave

        f32x4 sc[2];
        sc[0] = (f32x4)0.f; sc[1] = (f32x4)0.f;
#pragma unroll
        for (int n = 0; n < 2; ++n) {
            bf16x8 ak0 = *(bf16x8*)&Ks[n * 16 + l16][quad * 8];       // A-frag: row=kv(l16), k=d
            bf16x8 ak1 = *(bf16x8*)&Ks[n * 16 + l16][32 + quad * 8];
            sc[n] = __builtin_amdgcn_mfma_f32_16x16x32_bf16(ak0, aq0, sc[n], 0, 0, 0);
            sc[n] = __builtin_amdgcn_mfma_f32_16x16x32_bf16(ak1, aq1, sc[n], 0, 0, 0);
        }
        // sc[n][r]: score for kv = k0 + n*16 + quad*4 + r, q = qw + l16
        float pmax = MASKED;
#pragma unroll
        for (int n = 0; n < 2; ++n)
#pragma unroll
            for (int r = 0; r < 4; ++r) {
                int kv = k0 + n * 16 + quad * 4 + r;
                float sv = (kv <= qg) ? sc[n][r] * scale : MASKED;
                sc[n][r] = sv;
                pmax = fmaxf(pmax, sv);
            }
        pmax = fmaxf(pmax, __shfl_xor(pmax, 16));
        pmax = fmaxf(pmax, __shfl_xor(pmax, 32));
        float mnew = fmaxf(mrun, pmax);
        float ls = 0.f;
#pragma unroll
        for (int n = 0; n < 2; ++n)
#pragma unroll
            for (int r = 0; r < 4; ++r) {
                float pv = __expf(sc[n][r] - mnew);
                sc[n][r] = pv;
                ls += pv;
            }
        ls += __shfl_xor(ls, 16);
        ls += __shfl_xor(ls, 32);
        float alpha = __expf(mrun - mnew);
        lrun = lrun * alpha + ls;
        mrun = mnew;

        // pack P[q=l16][kv] to LDS, vectorized (conflict-free b64 writes)
        *(bf16x4*)&Ps[wave][l16][quad * 4]      = __builtin_convertvector(sc[0], bf16x4);
        *(bf16x4*)&Ps[wave][l16][16 + quad * 4] = __builtin_convertvector(sc[1], bf16x4);

        f32x4 av;
#pragma unroll
        for (int r = 0; r < 4; ++r) av[r] = __shfl(alpha, quad * 4 + r);

        bf16x8 pa = *(bf16x8*)&Ps[wave][l16][quad * 8];   // A-frag: row=q(l16), k=kv
#pragma unroll
        for (int n = 0; n < 4; ++n) {
            bf16x8 bv = *(bf16x8*)&Vt[n * 16 + l16][quad * 8];  // B-frag: col=d(l16), k=kv
            oacc[n] = __builtin_amdgcn_mfma_f32_16x16x32_bf16(pa, bv, oacc[n] * av, 0, 0, 0);
        }
    }

    float inv = 1.0f / lrun;
    f32x4 iv;
#pragma unroll
    for (int r = 0; r < 4; ++r) iv[r] = __shfl(inv, quad * 4 + r);
#pragma unroll
    for (int r = 0; r < 4; ++r) {
        long rowbase = (((long)b * S_ + qw + quad * 4 + r) * H_ + h) * HD_;
#pragma unroll
        for (int n = 0; n < 4; ++n)
            Ob[rowbase + n * 16 + l16] = (bf16_t)(oacc[n][r] * iv[r]);
    }
}

// ---------------- transpose + fp32->bf16 convert: W[Kd x Nd] -> Wt[Nd x Kd] ----------------
__global__ void tconv_kernel(const float* __restrict__ W, bf16_t* __restrict__ Wt,
                             int Kd, int Nd)
{
    __shared__ float t[32][33];
    int tx = threadIdx.x, ty = threadIdx.y;  // (32, 8)
    int bx = blockIdx.x, by = blockIdx.y;
#pragma unroll
    for (int i = 0; i < 4; ++i)
        t[ty + i * 8][tx] = W[(size_t)(by * 32 + ty + i * 8) * Nd + bx * 32 + tx];
    __syncthreads();
#pragma unroll
    for (int i = 0; i < 4; ++i)
        Wt[(size_t)(bx * 32 + ty + i * 8) * Kd + by * 32 + tx] = (bf16_t)t[tx][ty + i * 8];
}

// ---------------- bf16 MFMA GEMM: C[MxN] = A[MxK] * Bt[NxK]^T + bias ----------------
// BM=128 fixed, BN templated (128 or 64). grid.z = K-split; partial z -> Cf + z*pstride.
#define LDT 40
template<int BN>
__global__ __launch_bounds__(256) void gemm_bt_kernel(
    const bf16_t* __restrict__ A, const bf16_t* __restrict__ Bt,
    const float* __restrict__ bias, float* __restrict__ Cf,
    bf16_t* __restrict__ Cb, int M, int N, int K, int act, size_t pstride)
{
    __shared__ bf16_t As[128 * LDT];
    __shared__ bf16_t Bs[BN * LDT];
    int tid = threadIdx.x;
    int wave = tid >> 6, lane = tid & 63;
    int quad = lane >> 4, l16 = lane & 15;
    int m0 = blockIdx.x * 128;
    int n0 = blockIdx.y * BN;
    int Kc = K / gridDim.z;
    int kbeg = blockIdx.z * Kc;
    int kend = kbeg + Kc;
    float* Cfp = Cf ? Cf + (size_t)blockIdx.z * pstride : nullptr;

    constexpr int WN = BN / 2;       // wave tile N
    constexpr int NJ = WN / 16;      // 4 for BN=128, 2 for BN=64
    int wm = (wave >> 1) * 64, wn = (wave & 1) * WN;

    f32x4 acc[4][NJ];
#pragma unroll
    for (int i = 0; i < 4; ++i)
#pragma unroll
        for (int j = 0; j < NJ; ++j) acc[i][j] = (f32x4)0.f;

    for (int k0 = kbeg; k0 < kend; k0 += 32) {
        __syncthreads();
#pragma unroll
        for (int it = 0; it < 2; ++it) {
            int c = it * 256 + tid;          // [0,512)
            int row = c >> 2, col = (c & 3) * 8;
            *(bf16x8*)&As[row * LDT + col] =
                *(const bf16x8*)&A[(size_t)(m0 + row) * K + k0 + col];
        }
#pragma unroll
        for (int it = 0; it < BN / 64; ++it) {
            int c = it * 256 + tid;          // [0, BN*4)
            int row = c >> 2, col = (c & 3) * 8;
            *(bf16x8*)&Bs[row * LDT + col] =
                *(const bf16x8*)&Bt[(size_t)(n0 + row) * K + k0 + col];
        }
        __syncthreads();

        bf16x8 af[4], bfr[NJ];
#pragma unroll
        for (int i = 0; i < 4; ++i)
            af[i] = *(bf16x8*)&As[(wm + i * 16 + l16) * LDT + quad * 8];
#pragma unroll
        for (int j = 0; j < NJ; ++j)
            bfr[j] = *(bf16x8*)&Bs[(wn + j * 16 + l16) * LDT + quad * 8];
#pragma unroll
        for (int i = 0; i < 4; ++i)
#pragma unroll
            for (int j = 0; j < NJ; ++j)
                acc[i][j] = __builtin_amdgcn_mfma_f32_16x16x32_bf16(
                    af[i], bfr[j], acc[i][j], 0, 0, 0);
    }

#pragma unroll
    for (int j = 0; j < NJ; ++j) {
        int col = n0 + wn + j * 16 + l16;
        float bv = (bias && blockIdx.z == 0) ? bias[col] : 0.f;
#pragma unroll
        for (int i = 0; i < 4; ++i) {
            int rbase = m0 + wm + i * 16 + quad * 4;
#pragma unroll
            for (int r = 0; r < 4; ++r) {
                float vv = acc[i][j][r] + bv;
                if (act == 1) vv = gelu_exact(vv);
                if (Cfp) Cfp[(size_t)(rbase + r) * N + col] = vv;
                if (Cb) Cb[(size_t)(rbase + r) * N + col] = (bf16_t)vv;
            }
        }
    }
}

// ---------------- fused (partial-sum) residual add + LayerNorm (row = one block) ----------------
__global__ __launch_bounds__(256) void ln_fused_kernel(
    const float* __restrict__ a0, const float* __restrict__ a1,
    const float* __restrict__ b,
    const float* __restrict__ w, const float* __restrict__ beta,
    float* __restrict__ out, bf16_t* __restrict__ outb)
{
    long row = blockIdx.x;
    int tid = threadIdx.x;
    f32x4 z = *(const f32x4*)&a0[row * D_ + tid * 4];
    if (a1) z += *(const f32x4*)&a1[row * D_ + tid * 4];
    if (b)  z += *(const f32x4*)&b[row * D_ + tid * 4];
    float s  = z[0] + z[1] + z[2] + z[3];
    float ss = z[0]*z[0] + z[1]*z[1] + z[2]*z[2] + z[3]*z[3];
#pragma unroll
    for (int off = 32; off >= 1; off >>= 1) {
        s  += __shfl_down(s, off);
        ss += __shfl_down(ss, off);
    }
    __shared__ float red[8];
    int lane = tid & 63, wid = tid >> 6;
    if (lane == 0) { red[wid * 2] = s; red[wid * 2 + 1] = ss; }
    __syncthreads();
    s  = red[0] + red[2] + red[4] + red[6];
    ss = red[1] + red[3] + red[5] + red[7];
    float mean = s * (1.0f / D_);
    float var  = ss * (1.0f / D_) - mean * mean;
    float rs = rsqrtf(var + 1e-5f);
    f32x4 wv = *(const f32x4*)&w[tid * 4];
    f32x4 bv = *(const f32x4*)&beta[tid * 4];
    f32x4 o = (z - mean) * rs * wv + bv;
    *(f32x4*)&out[row * D_ + tid * 4] = o;
    if (outb) *(bf16x4*)&outb[row * D_ + tid * 4] = __builtin_convertvector(o, bf16x4);
}

// ---------------- host launch ----------------
extern "C" void kernel_launch(void* const* d_in, const int* in_sizes, int n_in,
                              void* d_out, int out_size, void* d_ws, size_t ws_size,
                              hipStream_t stream)
{
    (void)in_sizes; (void)n_in; (void)out_size; (void)ws_size;
    const float* x    = (const float*)d_in[0];
    const float* pos  = (const float*)d_in[1];
    const float* Wq   = (const float*)d_in[2];
    const float* bq   = (const float*)d_in[3];
    const float* Wk   = (const float*)d_in[4];
    const float* bk   = (const float*)d_in[5];
    const float* Wv   = (const float*)d_in[6];
    const float* bv   = (const float*)d_in[7];
    const float* Wfc  = (const float*)d_in[8];
    const float* bfc  = (const float*)d_in[9];
    const float* ln1w = (const float*)d_in[10];
    const float* ln1b = (const float*)d_in[11];
    const float* ln2w = (const float*)d_in[12];
    const float* ln2b = (const float*)d_in[13];
    const float* W1   = (const float*)d_in[14];
    const float* b1   = (const float*)d_in[15];
    const float* W2   = (const float*)d_in[16];
    const float* b2   = (const float*)d_in[17];
    const float* lnfw = (const float*)d_in[18];
    const float* lnfb = (const float*)d_in[19];

    const size_t MB = 1 << 20;
    char* ws = (char*)d_ws;
    float*  y    = (float*)(ws);             //  0-8   fp32 activations
    bf16_t* yb   = (bf16_t*)(ws + 8 * MB);   //  8-12  bf16 activations
    bf16_t* qb   = (bf16_t*)(ws + 12 * MB);  // 12-16
    bf16_t* kb   = (bf16_t*)(ws + 16 * MB);  // 16-20
    bf16_t* vb   = (bf16_t*)(ws + 20 * MB);  // 20-24
    bf16_t* ob   = (bf16_t*)(ws + 24 * MB);  // 24-28
    float*  t1a  = (float*)(ws + 12 * MB);   // 12-20  Wfc partial 0 (qb/kb dead after attn)
    float*  t1b  = (float*)(ws + 28 * MB);   // 28-36  Wfc partial 1 (aliases 'add'; ln1 reduces in place)
    float*  t2a  = (float*)(ws + 12 * MB);   // 12-20  FFN2 partial 0
    float*  t2b  = (float*)(ws + 20 * MB);   // 20-28  FFN2 partial 1 (vb/ob dead by then)
    float*  add  = (float*)(ws + 28 * MB);   // 28-36
    bf16_t* addb = (bf16_t*)(ws + 36 * MB);  // 36-40
    bf16_t* vTb  = (bf16_t*)(ws + 40 * MB);  // 40-44  V^T [b,h,d,s] (ffb region, dead here)
    bf16_t* ffb  = (bf16_t*)(ws + 40 * MB);  // 40-56
    bf16_t* WT   = (bf16_t*)(ws + 56 * MB);  // 56-64  per-layer weight transpose

    const size_t pstride_wfc  = (size_t)16 * MB / sizeof(float); // t1b - t1a
    const size_t pstride_ffn2 = (size_t)8 * MB / sizeof(float);  // t2b - t2a

    add_pos_kernel<<<2048, 256, 0, stream>>>(x, pos, y, yb);

    for (int i = 0; i < NL_; ++i) {
        qkv_mfma_kernel<<<256, 256, 0, stream>>>(
            yb, Wq + i * 4096, bq + i * 64, Wk + i * 4096, bk + i * 64,
            Wv + i * 4096, bv + i * 64, qb, kb, vb);

        vtrans_kernel<<<dim3(32, 32), 256, 0, stream>>>(vb, vTb);

        attn_mfma_kernel<<<dim3(16, 32), 256, 0, stream>>>(qb, kb, vTb, ob);

        // ---- attention output projection: split-K=2, BN=64 -> 512 blocks ----
        tconv_kernel<<<dim3(32, 32), dim3(32, 8), 0, stream>>>(
            Wfc + (size_t)i * D_ * D_, WT, D_, D_);
        gemm_bt_kernel<64><<<dim3(16, 16, 2), 256, 0, stream>>>(
            ob, WT, bfc + i * D_, t1a, nullptr, 2048, D_, D_, 0, pstride_wfc);

        ln_fused_kernel<<<2048, 256, 0, stream>>>(
            t1a, t1b, y, ln1w + i * D_, ln1b + i * D_, add, addb);

        // ---- FFN1: 512 blocks already, unchanged ----
        tconv_kernel<<<dim3(128, 32), dim3(32, 8), 0, stream>>>(
            W1 + (size_t)i * D_ * DFF_, WT, D_, DFF_);
        gemm_bt_kernel<128><<<dim3(16, 32, 1), 256, 0, stream>>>(
            addb, WT, b1 + i * DFF_, nullptr, ffb, 2048, DFF_, D_, 1, 0);

        // ---- FFN2: split-K=2, BN=64 -> 512 blocks ----
        tconv_kernel<<<dim3(32, 128), dim3(32, 8), 0, stream>>>(
            W2 + (size_t)i * DFF_ * D_, WT, DFF_, D_);
        gemm_bt_kernel<64><<<dim3(16, 16, 2), 256, 0, stream>>>(
            ffb, WT, b2 + i * D_, t2a, nullptr, 2048, D_, DFF_, 0, pstride_ffn2);

        ln_fused_kernel<<<2048, 256, 0, stream>>>(
            t2a, t2b, add, ln2w + i * D_, ln2b + i * D_, y, yb);
    }

    ln_fused_kernel<<<2048, 256, 0, stream>>>(
        y, nullptr, nullptr, lnfw, lnfb, (float*)d_out, nullptr);
}

// Round 4
// 1293.663 us; speedup vs baseline: 1.3706x; 1.0463x over previous
//
#include <hip/hip_runtime.h>
#include <hip/hip_bf16.h>
#include <math.h>

#define B_   2
#define S_   1024
#define D_   1024
#define H_   16
#define HD_  64
#define NL_  6
#define DFF_ 4096

typedef __bf16 bf16_t;
typedef bf16_t bf16x8 __attribute__((ext_vector_type(8)));
typedef bf16_t bf16x4 __attribute__((ext_vector_type(4)));
typedef float  f32x4  __attribute__((ext_vector_type(4)));

__device__ __forceinline__ float gelu_exact(float x) {
    return 0.5f * x * (1.0f + erff(x * 0.70710678118654752f));
}

// async global->LDS, 16B per lane; LDS dest is wave-uniform base + lane*16
__device__ __forceinline__ void gload16(const bf16_t* g, bf16_t* l) {
    __builtin_amdgcn_global_load_lds(
        (const __attribute__((address_space(1))) void*)g,
        (__attribute__((address_space(3))) void*)l, 16, 0, 0);
}

// ---------------- y = x + pos (pos broadcast over batch); fp32 + bf16 out ----------------
__global__ __launch_bounds__(256) void add_pos_kernel(
    const float* __restrict__ x, const float* __restrict__ pos,
    float* __restrict__ y, bf16_t* __restrict__ yb)
{
    int idx = blockIdx.x * 256 + threadIdx.x;      // float4 index, [0, 524288)
    f32x4 xv = *(const f32x4*)&x[idx * 4];
    f32x4 pv = *(const f32x4*)&pos[(idx & 262143) * 4];  // S*D/4 = 262144
    f32x4 o = xv + pv;
    *(f32x4*)&y[idx * 4] = o;
    *(bf16x4*)&yb[idx * 4] = __builtin_convertvector(o, bf16x4);
}

// ---------------- QKV projection via MFMA ----------------
__global__ __launch_bounds__(256) void qkv_mfma_kernel(
    const bf16_t* __restrict__ yb,
    const float* __restrict__ Wq, const float* __restrict__ bq,
    const float* __restrict__ Wk, const float* __restrict__ bk,
    const float* __restrict__ Wv, const float* __restrict__ bv,
    bf16_t* __restrict__ q, bf16_t* __restrict__ k, bf16_t* __restrict__ v)
{
    __shared__ __align__(16) bf16_t As[128][72];
    __shared__ __align__(16) bf16_t Wt[3][64][72];   // W^T: [n][k], bf16

    int tid = threadIdx.x;
    long m0 = (long)blockIdx.x * 128;

#pragma unroll
    for (int it = 0; it < 4; ++it) {
        int c = it * 256 + tid;            // [0,1024) x8 elems
        int row = c >> 3, col = (c & 7) * 8;
        *(bf16x8*)&As[row][col] = *(const bf16x8*)&yb[(m0 + row) * 64 + col];
    }
#pragma unroll
    for (int it = 0; it < 16; ++it) {
        int i = it * 256 + tid;            // [0,4096)
        int r = i >> 6, c = i & 63;
        Wt[0][c][r] = (bf16_t)Wq[i];
        Wt[1][c][r] = (bf16_t)Wk[i];
        Wt[2][c][r] = (bf16_t)Wv[i];
    }
    __syncthreads();

    int wave = tid >> 6, lane = tid & 63;
    int quad = lane >> 4, l16 = lane & 15;
    int wm = wave * 32;

    bf16x8 a[2][2];
#pragma unroll
    for (int i = 0; i < 2; ++i)
#pragma unroll
        for (int ks = 0; ks < 2; ++ks)
            a[i][ks] = *(bf16x8*)&As[wm + i * 16 + l16][ks * 32 + quad * 8];

    f32x4 acc[3][2][4];
#pragma unroll
    for (int o = 0; o < 3; ++o)
#pragma unroll
        for (int i = 0; i < 2; ++i)
#pragma unroll
            for (int j = 0; j < 4; ++j) acc[o][i][j] = (f32x4)0.f;

#pragma unroll
    for (int o = 0; o < 3; ++o)
#pragma unroll
        for (int j = 0; j < 4; ++j) {
            bf16x8 b0 = *(bf16x8*)&Wt[o][j * 16 + l16][quad * 8];
            bf16x8 b1 = *(bf16x8*)&Wt[o][j * 16 + l16][32 + quad * 8];
#pragma unroll
            for (int i = 0; i < 2; ++i) {
                acc[o][i][j] = __builtin_amdgcn_mfma_f32_16x16x32_bf16(a[i][0], b0, acc[o][i][j], 0, 0, 0);
                acc[o][i][j] = __builtin_amdgcn_mfma_f32_16x16x32_bf16(a[i][1], b1, acc[o][i][j], 0, 0, 0);
            }
        }

    bf16_t* outs[3] = { q, k, v };
    const float* biases[3] = { bq, bk, bv };
#pragma unroll
    for (int o = 0; o < 3; ++o)
#pragma unroll
        for (int j = 0; j < 4; ++j) {
            int col = j * 16 + l16;
            float bias = biases[o][col];
#pragma unroll
            for (int i = 0; i < 2; ++i) {
                long rbase = m0 + wm + i * 16 + quad * 4;
#pragma unroll
                for (int r = 0; r < 4; ++r)
                    outs[o][(rbase + r) * 64 + col] = (bf16_t)(acc[o][i][j][r] + bias);
            }
        }
}

// ---------------- V transpose: vb [b,s,h,d] -> vT [b,h,d,s] ----------------
__global__ __launch_bounds__(256) void vtrans_kernel(
    const bf16_t* __restrict__ vb, bf16_t* __restrict__ vT)
{
    __shared__ __align__(16) bf16_t L[32][72];
    int tid = threadIdx.x;
    int s0 = blockIdx.x * 32;
    int bh = blockIdx.y;
    int b = bh >> 4, h = bh & 15;
    int sr = tid >> 3, dc = (tid & 7) * 8;
    *(bf16x8*)&L[sr][dc] =
        *(const bf16x8*)&vb[(((long)b * S_ + s0 + sr) * H_ + h) * HD_ + dc];
    __syncthreads();
    int dr = tid >> 2, sg = (tid & 3) * 8;
    bf16x8 o;
#pragma unroll
    for (int j = 0; j < 8; ++j) o[j] = L[sg + j][dr];
    *(bf16x8*)&vT[((long)bh * HD_ + dr) * S_ + s0 + sg] = o;
}

// ---------------- causal flash attention, swapped-QK bf16 MFMA, 64q x 32kv ----------------
__global__ __launch_bounds__(256) void attn_mfma_kernel(
    const bf16_t* __restrict__ Q, const bf16_t* __restrict__ K,
    const bf16_t* __restrict__ VT, bf16_t* __restrict__ Ob)
{
    __shared__ __align__(16) bf16_t Ks[32][72];       // [kv][d]
    __shared__ __align__(16) bf16_t Vt[64][40];       // [d][kv]
    __shared__ __align__(16) bf16_t Ps[4][16][40];    // per-wave P tile [q][kv]

    int tid = threadIdx.x;
    int wave = tid >> 6, lane = tid & 63;
    int quad = lane >> 4, l16 = lane & 15;
    int q0 = blockIdx.x * 64;
    int bh = blockIdx.y;
    int b = bh >> 4, h = bh & 15;
    int qw = q0 + wave * 16;
    const float scale = 0.125f;             // 1/sqrt(64)
    const float MASKED = -1.25e19f;         // -1e20 * scale, per reference order

    const bf16_t* Qbase = Q + (((long)b * S_ + qw + l16) * H_ + h) * HD_;
    bf16x8 aq0 = *(const bf16x8*)&Qbase[quad * 8];        // B-frag: col=q(l16), k=d
    bf16x8 aq1 = *(const bf16x8*)&Qbase[32 + quad * 8];

    float mrun = -3.0e38f, lrun = 0.f;      // state for q = qw + l16 (replicated over quads)
    f32x4 oacc[4];
#pragma unroll
    for (int n = 0; n < 4; ++n) oacc[n] = (f32x4)0.f;

    int srow = tid >> 3, scol = (tid & 7) * 8;   // K staging: 32 kv x 64 d
    int vdr = tid >> 2, vkg = (tid & 3) * 8;     // V^T staging: 64 d x 32 kv
    const bf16_t* VTbase = VT + ((long)bh * HD_ + vdr) * S_ + vkg;
    int qg = qw + l16;

    int nkt = (q0 + 64) / 32;
    for (int kt = 0; kt < nkt; ++kt) {
        int k0 = kt * 32;
        __syncthreads();
        *(bf16x8*)&Ks[srow][scol] =
            *(const bf16x8*)&K[(((long)b * S_ + k0 + srow) * H_ + h) * HD_ + scol];
        *(bf16x8*)&Vt[vdr][vkg] = *(const bf16x8*)&VTbase[k0];
        __syncthreads();

        if (k0 > qw + 15) continue;          // fully-masked tile for this wave

        f32x4 sc[2];
        sc[0] = (f32x4)0.f; sc[1] = (f32x4)0.f;
#pragma unroll
        for (int n = 0; n < 2; ++n) {
            bf16x8 ak0 = *(bf16x8*)&Ks[n * 16 + l16][quad * 8];       // A-frag: row=kv(l16), k=d
            bf16x8 ak1 = *(bf16x8*)&Ks[n * 16 + l16][32 + quad * 8];
            sc[n] = __builtin_amdgcn_mfma_f32_16x16x32_bf16(ak0, aq0, sc[n], 0, 0, 0);
            sc[n] = __builtin_amdgcn_mfma_f32_16x16x32_bf16(ak1, aq1, sc[n], 0, 0, 0);
        }
        float pmax = MASKED;
#pragma unroll
        for (int n = 0; n < 2; ++n)
#pragma unroll
            for (int r = 0; r < 4; ++r) {
                int kv = k0 + n * 16 + quad * 4 + r;
                float sv = (kv <= qg) ? sc[n][r] * scale : MASKED;
                sc[n][r] = sv;
                pmax = fmaxf(pmax, sv);
            }
        pmax = fmaxf(pmax, __shfl_xor(pmax, 16));
        pmax = fmaxf(pmax, __shfl_xor(pmax, 32));
        float mnew = fmaxf(mrun, pmax);
        float ls = 0.f;
#pragma unroll
        for (int n = 0; n < 2; ++n)
#pragma unroll
            for (int r = 0; r < 4; ++r) {
                float pv = __expf(sc[n][r] - mnew);
                sc[n][r] = pv;
                ls += pv;
            }
        ls += __shfl_xor(ls, 16);
        ls += __shfl_xor(ls, 32);
        float alpha = __expf(mrun - mnew);
        lrun = lrun * alpha + ls;
        mrun = mnew;

        *(bf16x4*)&Ps[wave][l16][quad * 4]      = __builtin_convertvector(sc[0], bf16x4);
        *(bf16x4*)&Ps[wave][l16][16 + quad * 4] = __builtin_convertvector(sc[1], bf16x4);

        f32x4 av;
#pragma unroll
        for (int r = 0; r < 4; ++r) av[r] = __shfl(alpha, quad * 4 + r);

        bf16x8 pa = *(bf16x8*)&Ps[wave][l16][quad * 8];   // A-frag: row=q(l16), k=kv
#pragma unroll
        for (int n = 0; n < 4; ++n) {
            bf16x8 bv = *(bf16x8*)&Vt[n * 16 + l16][quad * 8];  // B-frag: col=d(l16), k=kv
            oacc[n] = __builtin_amdgcn_mfma_f32_16x16x32_bf16(pa, bv, oacc[n] * av, 0, 0, 0);
        }
    }

    float inv = 1.0f / lrun;
    f32x4 iv;
#pragma unroll
    for (int r = 0; r < 4; ++r) iv[r] = __shfl(inv, quad * 4 + r);
#pragma unroll
    for (int r = 0; r < 4; ++r) {
        long rowbase = (((long)b * S_ + qw + quad * 4 + r) * H_ + h) * HD_;
#pragma unroll
        for (int n = 0; n < 4; ++n)
            Ob[rowbase + n * 16 + l16] = (bf16_t)(oacc[n][r] * iv[r]);
    }
}

// ---------------- transpose + fp32->bf16 convert: W[Kd x Nd] -> Wt[Nd x Kd] ----------------
__global__ void tconv_kernel(const float* __restrict__ W, bf16_t* __restrict__ Wt,
                             int Kd, int Nd)
{
    __shared__ float t[32][33];
    int tx = threadIdx.x, ty = threadIdx.y;  // (32, 8)
    int bx = blockIdx.x, by = blockIdx.y;
#pragma unroll
    for (int i = 0; i < 4; ++i)
        t[ty + i * 8][tx] = W[(size_t)(by * 32 + ty + i * 8) * Nd + bx * 32 + tx];
    __syncthreads();
#pragma unroll
    for (int i = 0; i < 4; ++i)
        Wt[(size_t)(bx * 32 + ty + i * 8) * Kd + by * 32 + tx] = (bf16_t)t[tx][ty + i * 8];
}

// ---------------- bf16 MFMA GEMM: C[MxN] = A[MxK] * Bt[NxK]^T + bias ----------------
// BM=128, BN=64, BK=32. global_load_lds(16B) staging into LINEAR LDS [rows][32],
// with 4-slot XOR swizzle applied to the GLOBAL source and the ds_read (rule 21:
// linear dest + inverse-swz source + swz read). grid.z = K-split; partial z ->
// Cf + z*pstride; bias only in split 0 (downstream ln sums partials).
__global__ __launch_bounds__(256) void gemm_bt_kernel(
    const bf16_t* __restrict__ A, const bf16_t* __restrict__ Bt,
    const float* __restrict__ bias, float* __restrict__ Cf,
    bf16_t* __restrict__ Cb, int M, int N, int K, int act, size_t pstride)
{
    __shared__ __align__(16) bf16_t As[128 * 32];   // 8 KB, linear [row][32]
    __shared__ __align__(16) bf16_t Bs[64 * 32];    // 4 KB, linear [row][32]
    int tid = threadIdx.x;
    int wave = tid >> 6, lane = tid & 63;
    int quad = lane >> 4, l16 = lane & 15;
    int m0 = blockIdx.x * 128;
    int n0 = blockIdx.y * 64;
    int Kc = K / gridDim.z;
    int kbeg = blockIdx.z * Kc;
    int kend = kbeg + Kc;
    float* Cfp = Cf ? Cf + (size_t)blockIdx.z * pstride : nullptr;

    int wm = (wave >> 1) * 64, wn = (wave & 1) * 32;

    // staging geometry: each wave-load covers 16 rows x 32 cols (1024 B);
    // lane -> row seg*16 + (lane>>2), linear slot lane&3; source col-slot XOR'd.
    int srow = lane >> 2;
    int sslot = (lane & 3) ^ (srow & 3);          // pre-swizzled global source slot
    // read-side swizzle: logical slot quad of row r lives at slot quad^(r&3); r&3 = l16&3
    int rslot = (quad ^ (l16 & 3)) * 8;

    f32x4 acc[4][2];
#pragma unroll
    for (int i = 0; i < 4; ++i)
#pragma unroll
        for (int j = 0; j < 2; ++j) acc[i][j] = (f32x4)0.f;

    const bf16_t* Ab = A + (size_t)(m0 + srow) * K + sslot * 8;
    const bf16_t* Bb = Bt + (size_t)(n0 + wave * 16 + srow) * K + sslot * 8;

    for (int k0 = kbeg; k0 < kend; k0 += 32) {
        __syncthreads();
        // A: 8 segments of 16 rows; wave w stages segs {2w, 2w+1}
#pragma unroll
        for (int t = 0; t < 2; ++t) {
            int seg = wave * 2 + t;
            gload16(Ab + (size_t)seg * 16 * K + k0, &As[seg * 512]);
        }
        // B: 4 segments; wave w stages seg w
        gload16(Bb + k0, &Bs[wave * 512]);
        __syncthreads();

        bf16x8 af[4], bfr[2];
#pragma unroll
        for (int i = 0; i < 4; ++i)
            af[i] = *(bf16x8*)&As[(wm + i * 16 + l16) * 32 + rslot];
#pragma unroll
        for (int j = 0; j < 2; ++j)
            bfr[j] = *(bf16x8*)&Bs[(wn + j * 16 + l16) * 32 + rslot];
#pragma unroll
        for (int i = 0; i < 4; ++i)
#pragma unroll
            for (int j = 0; j < 2; ++j)
                acc[i][j] = __builtin_amdgcn_mfma_f32_16x16x32_bf16(
                    af[i], bfr[j], acc[i][j], 0, 0, 0);
    }

#pragma unroll
    for (int j = 0; j < 2; ++j) {
        int col = n0 + wn + j * 16 + l16;
        float bv = (bias && blockIdx.z == 0) ? bias[col] : 0.f;
#pragma unroll
        for (int i = 0; i < 4; ++i) {
            int rbase = m0 + wm + i * 16 + quad * 4;
#pragma unroll
            for (int r = 0; r < 4; ++r) {
                float vv = acc[i][j][r] + bv;
                if (act == 1) vv = gelu_exact(vv);
                if (Cfp) Cfp[(size_t)(rbase + r) * N + col] = vv;
                if (Cb) Cb[(size_t)(rbase + r) * N + col] = (bf16_t)vv;
            }
        }
    }
}

// ---------------- fused (partial-sum) residual add + LayerNorm (row = one block) ----------------
__global__ __launch_bounds__(256) void ln_fused_kernel(
    const float* __restrict__ a0, const float* __restrict__ a1,
    const float* __restrict__ b,
    const float* __restrict__ w, const float* __restrict__ beta,
    float* __restrict__ out, bf16_t* __restrict__ outb)
{
    long row = blockIdx.x;
    int tid = threadIdx.x;
    f32x4 z = *(const f32x4*)&a0[row * D_ + tid * 4];
    if (a1) z += *(const f32x4*)&a1[row * D_ + tid * 4];
    if (b)  z += *(const f32x4*)&b[row * D_ + tid * 4];
    float s  = z[0] + z[1] + z[2] + z[3];
    float ss = z[0]*z[0] + z[1]*z[1] + z[2]*z[2] + z[3]*z[3];
#pragma unroll
    for (int off = 32; off >= 1; off >>= 1) {
        s  += __shfl_down(s, off);
        ss += __shfl_down(ss, off);
    }
    __shared__ float red[8];
    int lane = tid & 63, wid = tid >> 6;
    if (lane == 0) { red[wid * 2] = s; red[wid * 2 + 1] = ss; }
    __syncthreads();
    s  = red[0] + red[2] + red[4] + red[6];
    ss = red[1] + red[3] + red[5] + red[7];
    float mean = s * (1.0f / D_);
    float var  = ss * (1.0f / D_) - mean * mean;
    float rs = rsqrtf(var + 1e-5f);
    f32x4 wv = *(const f32x4*)&w[tid * 4];
    f32x4 bv = *(const f32x4*)&beta[tid * 4];
    f32x4 o = (z - mean) * rs * wv + bv;
    *(f32x4*)&out[row * D_ + tid * 4] = o;
    if (outb) *(bf16x4*)&outb[row * D_ + tid * 4] = __builtin_convertvector(o, bf16x4);
}

// ---------------- host launch ----------------
extern "C" void kernel_launch(void* const* d_in, const int* in_sizes, int n_in,
                              void* d_out, int out_size, void* d_ws, size_t ws_size,
                              hipStream_t stream)
{
    (void)in_sizes; (void)n_in; (void)out_size; (void)ws_size;
    const float* x    = (const float*)d_in[0];
    const float* pos  = (const float*)d_in[1];
    const float* Wq   = (const float*)d_in[2];
    const float* bq   = (const float*)d_in[3];
    const float* Wk   = (const float*)d_in[4];
    const float* bk   = (const float*)d_in[5];
    const float* Wv   = (const float*)d_in[6];
    const float* bv   = (const float*)d_in[7];
    const float* Wfc  = (const float*)d_in[8];
    const float* bfc  = (const float*)d_in[9];
    const float* ln1w = (const float*)d_in[10];
    const float* ln1b = (const float*)d_in[11];
    const float* ln2w = (const float*)d_in[12];
    const float* ln2b = (const float*)d_in[13];
    const float* W1   = (const float*)d_in[14];
    const float* b1   = (const float*)d_in[15];
    const float* W2   = (const float*)d_in[16];
    const float* b2   = (const float*)d_in[17];
    const float* lnfw = (const float*)d_in[18];
    const float* lnfb = (const float*)d_in[19];

    const size_t MB = 1 << 20;
    char* ws = (char*)d_ws;
    float*  y    = (float*)(ws);             //  0-8   fp32 activations
    bf16_t* yb   = (bf16_t*)(ws + 8 * MB);   //  8-12  bf16 activations
    bf16_t* qb   = (bf16_t*)(ws + 12 * MB);  // 12-16
    bf16_t* kb   = (bf16_t*)(ws + 16 * MB);  // 16-20
    bf16_t* vb   = (bf16_t*)(ws + 20 * MB);  // 20-24
    bf16_t* ob   = (bf16_t*)(ws + 24 * MB);  // 24-28
    float*  t1a  = (float*)(ws + 12 * MB);   // 12-20  Wfc partial 0 (qb/kb dead after attn)
    float*  t1b  = (float*)(ws + 28 * MB);   // 28-36  Wfc partial 1 (aliases 'add'; ln1 reduces in place)
    float*  t2a  = (float*)(ws + 12 * MB);   // 12-20  FFN2 partial 0
    float*  t2b  = (float*)(ws + 20 * MB);   // 20-28  FFN2 partial 1 (vb/ob dead by then)
    float*  add  = (float*)(ws + 28 * MB);   // 28-36
    bf16_t* addb = (bf16_t*)(ws + 36 * MB);  // 36-40
    bf16_t* vTb  = (bf16_t*)(ws + 40 * MB);  // 40-44  V^T [b,h,d,s] (ffb region, dead here)
    bf16_t* ffb  = (bf16_t*)(ws + 40 * MB);  // 40-56
    bf16_t* WT   = (bf16_t*)(ws + 56 * MB);  // 56-64  per-layer weight transpose

    const size_t pstride_wfc  = (size_t)16 * MB / sizeof(float); // t1b - t1a
    const size_t pstride_ffn2 = (size_t)8 * MB / sizeof(float);  // t2b - t2a

    add_pos_kernel<<<2048, 256, 0, stream>>>(x, pos, y, yb);

    for (int i = 0; i < NL_; ++i) {
        qkv_mfma_kernel<<<256, 256, 0, stream>>>(
            yb, Wq + i * 4096, bq + i * 64, Wk + i * 4096, bk + i * 64,
            Wv + i * 4096, bv + i * 64, qb, kb, vb);

        vtrans_kernel<<<dim3(32, 32), 256, 0, stream>>>(vb, vTb);

        attn_mfma_kernel<<<dim3(16, 32), 256, 0, stream>>>(qb, kb, vTb, ob);

        // ---- attention output projection: split-K=2, BN=64 -> 512 blocks ----
        tconv_kernel<<<dim3(32, 32), dim3(32, 8), 0, stream>>>(
            Wfc + (size_t)i * D_ * D_, WT, D_, D_);
        gemm_bt_kernel<<<dim3(16, 16, 2), 256, 0, stream>>>(
            ob, WT, bfc + i * D_, t1a, nullptr, 2048, D_, D_, 0, pstride_wfc);

        ln_fused_kernel<<<2048, 256, 0, stream>>>(
            t1a, t1b, y, ln1w + i * D_, ln1b + i * D_, add, addb);

        // ---- FFN1: BN=64 -> 1024 blocks (4 blocks/CU) ----
        tconv_kernel<<<dim3(128, 32), dim3(32, 8), 0, stream>>>(
            W1 + (size_t)i * D_ * DFF_, WT, D_, DFF_);
        gemm_bt_kernel<<<dim3(16, 64, 1), 256, 0, stream>>>(
            addb, WT, b1 + i * DFF_, nullptr, ffb, 2048, DFF_, D_, 1, 0);

        // ---- FFN2: split-K=2, BN=64 -> 512 blocks ----
        tconv_kernel<<<dim3(32, 128), dim3(32, 8), 0, stream>>>(
            W2 + (size_t)i * DFF_ * D_, WT, DFF_, D_);
        gemm_bt_kernel<<<dim3(16, 16, 2), 256, 0, stream>>>(
            ffb, WT, b2 + i * D_, t2a, nullptr, 2048, D_, DFF_, 0, pstride_ffn2);

        ln_fused_kernel<<<2048, 256, 0, stream>>>(
            t2a, t2b, add, ln2w + i * D_, ln2b + i * D_, y, yb);
    }

    ln_fused_kernel<<<2048, 256, 0, stream>>>(
        y, nullptr, nullptr, lnfw, lnfb, (float*)d_out, nullptr);
}

// Round 5
// 1268.192 us; speedup vs baseline: 1.3981x; 1.0201x over previous
//
#include <hip/hip_runtime.h>
#include <hip/hip_bf16.h>
#include <math.h>

#define B_   2
#define S_   1024
#define D_   1024
#define H_   16
#define HD_  64
#define NL_  6
#define DFF_ 4096

typedef __bf16 bf16_t;
typedef bf16_t bf16x8 __attribute__((ext_vector_type(8)));
typedef bf16_t bf16x4 __attribute__((ext_vector_type(4)));
typedef float  f32x4  __attribute__((ext_vector_type(4)));

__device__ __forceinline__ float gelu_exact(float x) {
    return 0.5f * x * (1.0f + erff(x * 0.70710678118654752f));
}

// async global->LDS, 16B per lane; LDS dest is wave-uniform base + lane*16
__device__ __forceinline__ void gload16(const bf16_t* g, bf16_t* l) {
    __builtin_amdgcn_global_load_lds(
        (const __attribute__((address_space(1))) void*)g,
        (__attribute__((address_space(3))) void*)l, 16, 0, 0);
}

// ---------------- y = x + pos (pos broadcast over batch); fp32 + bf16 out ----------------
__global__ __launch_bounds__(256) void add_pos_kernel(
    const float* __restrict__ x, const float* __restrict__ pos,
    float* __restrict__ y, bf16_t* __restrict__ yb)
{
    int idx = blockIdx.x * 256 + threadIdx.x;      // float4 index, [0, 524288)
    f32x4 xv = *(const f32x4*)&x[idx * 4];
    f32x4 pv = *(const f32x4*)&pos[(idx & 262143) * 4];  // S*D/4 = 262144
    f32x4 o = xv + pv;
    *(f32x4*)&y[idx * 4] = o;
    *(bf16x4*)&yb[idx * 4] = __builtin_convertvector(o, bf16x4);
}

// ---------------- QKV projection via MFMA ----------------
__global__ __launch_bounds__(256) void qkv_mfma_kernel(
    const bf16_t* __restrict__ yb,
    const float* __restrict__ Wq, const float* __restrict__ bq,
    const float* __restrict__ Wk, const float* __restrict__ bk,
    const float* __restrict__ Wv, const float* __restrict__ bv,
    bf16_t* __restrict__ q, bf16_t* __restrict__ k, bf16_t* __restrict__ v)
{
    __shared__ __align__(16) bf16_t As[128][72];
    __shared__ __align__(16) bf16_t Wt[3][64][72];   // W^T: [n][k], bf16

    int tid = threadIdx.x;
    long m0 = (long)blockIdx.x * 128;

#pragma unroll
    for (int it = 0; it < 4; ++it) {
        int c = it * 256 + tid;            // [0,1024) x8 elems
        int row = c >> 3, col = (c & 7) * 8;
        *(bf16x8*)&As[row][col] = *(const bf16x8*)&yb[(m0 + row) * 64 + col];
    }
#pragma unroll
    for (int it = 0; it < 16; ++it) {
        int i = it * 256 + tid;            // [0,4096)
        int r = i >> 6, c = i & 63;
        Wt[0][c][r] = (bf16_t)Wq[i];
        Wt[1][c][r] = (bf16_t)Wk[i];
        Wt[2][c][r] = (bf16_t)Wv[i];
    }
    __syncthreads();

    int wave = tid >> 6, lane = tid & 63;
    int quad = lane >> 4, l16 = lane & 15;
    int wm = wave * 32;

    bf16x8 a[2][2];
#pragma unroll
    for (int i = 0; i < 2; ++i)
#pragma unroll
        for (int ks = 0; ks < 2; ++ks)
            a[i][ks] = *(bf16x8*)&As[wm + i * 16 + l16][ks * 32 + quad * 8];

    f32x4 acc[3][2][4];
#pragma unroll
    for (int o = 0; o < 3; ++o)
#pragma unroll
        for (int i = 0; i < 2; ++i)
#pragma unroll
            for (int j = 0; j < 4; ++j) acc[o][i][j] = (f32x4)0.f;

#pragma unroll
    for (int o = 0; o < 3; ++o)
#pragma unroll
        for (int j = 0; j < 4; ++j) {
            bf16x8 b0 = *(bf16x8*)&Wt[o][j * 16 + l16][quad * 8];
            bf16x8 b1 = *(bf16x8*)&Wt[o][j * 16 + l16][32 + quad * 8];
#pragma unroll
            for (int i = 0; i < 2; ++i) {
                acc[o][i][j] = __builtin_amdgcn_mfma_f32_16x16x32_bf16(a[i][0], b0, acc[o][i][j], 0, 0, 0);
                acc[o][i][j] = __builtin_amdgcn_mfma_f32_16x16x32_bf16(a[i][1], b1, acc[o][i][j], 0, 0, 0);
            }
        }

    bf16_t* outs[3] = { q, k, v };
    const float* biases[3] = { bq, bk, bv };
#pragma unroll
    for (int o = 0; o < 3; ++o)
#pragma unroll
        for (int j = 0; j < 4; ++j) {
            int col = j * 16 + l16;
            float bias = biases[o][col];
#pragma unroll
            for (int i = 0; i < 2; ++i) {
                long rbase = m0 + wm + i * 16 + quad * 4;
#pragma unroll
                for (int r = 0; r < 4; ++r)
                    outs[o][(rbase + r) * 64 + col] = (bf16_t)(acc[o][i][j][r] + bias);
            }
        }
}

// ---------------- V transpose: vb [b,s,h,d] -> vT [b,h,d,s] ----------------
__global__ __launch_bounds__(256) void vtrans_kernel(
    const bf16_t* __restrict__ vb, bf16_t* __restrict__ vT)
{
    __shared__ __align__(16) bf16_t L[32][72];
    int tid = threadIdx.x;
    int s0 = blockIdx.x * 32;
    int bh = blockIdx.y;
    int b = bh >> 4, h = bh & 15;
    int sr = tid >> 3, dc = (tid & 7) * 8;
    *(bf16x8*)&L[sr][dc] =
        *(const bf16x8*)&vb[(((long)b * S_ + s0 + sr) * H_ + h) * HD_ + dc];
    __syncthreads();
    int dr = tid >> 2, sg = (tid & 3) * 8;
    bf16x8 o;
#pragma unroll
    for (int j = 0; j < 8; ++j) o[j] = L[sg + j][dr];
    *(bf16x8*)&vT[((long)bh * HD_ + dr) * S_ + s0 + sg] = o;
}

// ---------------- causal flash attention, swapped-QK bf16 MFMA, 64q x 32kv ----------------
__global__ __launch_bounds__(256) void attn_mfma_kernel(
    const bf16_t* __restrict__ Q, const bf16_t* __restrict__ K,
    const bf16_t* __restrict__ VT, bf16_t* __restrict__ Ob)
{
    __shared__ __align__(16) bf16_t Ks[32][72];       // [kv][d]
    __shared__ __align__(16) bf16_t Vt[64][40];       // [d][kv]
    __shared__ __align__(16) bf16_t Ps[4][16][40];    // per-wave P tile [q][kv]

    int tid = threadIdx.x;
    int wave = tid >> 6, lane = tid & 63;
    int quad = lane >> 4, l16 = lane & 15;
    int q0 = blockIdx.x * 64;
    int bh = blockIdx.y;
    int b = bh >> 4, h = bh & 15;
    int qw = q0 + wave * 16;
    const float scale = 0.125f;             // 1/sqrt(64)
    const float MASKED = -1.25e19f;         // -1e20 * scale, per reference order

    const bf16_t* Qbase = Q + (((long)b * S_ + qw + l16) * H_ + h) * HD_;
    bf16x8 aq0 = *(const bf16x8*)&Qbase[quad * 8];        // B-frag: col=q(l16), k=d
    bf16x8 aq1 = *(const bf16x8*)&Qbase[32 + quad * 8];

    float mrun = -3.0e38f, lrun = 0.f;      // state for q = qw + l16 (replicated over quads)
    f32x4 oacc[4];
#pragma unroll
    for (int n = 0; n < 4; ++n) oacc[n] = (f32x4)0.f;

    int srow = tid >> 3, scol = (tid & 7) * 8;   // K staging: 32 kv x 64 d
    int vdr = tid >> 2, vkg = (tid & 3) * 8;     // V^T staging: 64 d x 32 kv
    const bf16_t* VTbase = VT + ((long)bh * HD_ + vdr) * S_ + vkg;
    int qg = qw + l16;

    int nkt = (q0 + 64) / 32;
    for (int kt = 0; kt < nkt; ++kt) {
        int k0 = kt * 32;
        __syncthreads();
        *(bf16x8*)&Ks[srow][scol] =
            *(const bf16x8*)&K[(((long)b * S_ + k0 + srow) * H_ + h) * HD_ + scol];
        *(bf16x8*)&Vt[vdr][vkg] = *(const bf16x8*)&VTbase[k0];
        __syncthreads();

        if (k0 > qw + 15) continue;          // fully-masked tile for this wave

        f32x4 sc[2];
        sc[0] = (f32x4)0.f; sc[1] = (f32x4)0.f;
#pragma unroll
        for (int n = 0; n < 2; ++n) {
            bf16x8 ak0 = *(bf16x8*)&Ks[n * 16 + l16][quad * 8];       // A-frag: row=kv(l16), k=d
            bf16x8 ak1 = *(bf16x8*)&Ks[n * 16 + l16][32 + quad * 8];
            sc[n] = __builtin_amdgcn_mfma_f32_16x16x32_bf16(ak0, aq0, sc[n], 0, 0, 0);
            sc[n] = __builtin_amdgcn_mfma_f32_16x16x32_bf16(ak1, aq1, sc[n], 0, 0, 0);
        }
        float pmax = MASKED;
#pragma unroll
        for (int n = 0; n < 2; ++n)
#pragma unroll
            for (int r = 0; r < 4; ++r) {
                int kv = k0 + n * 16 + quad * 4 + r;
                float sv = (kv <= qg) ? sc[n][r] * scale : MASKED;
                sc[n][r] = sv;
                pmax = fmaxf(pmax, sv);
            }
        pmax = fmaxf(pmax, __shfl_xor(pmax, 16));
        pmax = fmaxf(pmax, __shfl_xor(pmax, 32));
        float mnew = fmaxf(mrun, pmax);
        float ls = 0.f;
#pragma unroll
        for (int n = 0; n < 2; ++n)
#pragma unroll
            for (int r = 0; r < 4; ++r) {
                float pv = __expf(sc[n][r] - mnew);
                sc[n][r] = pv;
                ls += pv;
            }
        ls += __shfl_xor(ls, 16);
        ls += __shfl_xor(ls, 32);
        float alpha = __expf(mrun - mnew);
        lrun = lrun * alpha + ls;
        mrun = mnew;

        *(bf16x4*)&Ps[wave][l16][quad * 4]      = __builtin_convertvector(sc[0], bf16x4);
        *(bf16x4*)&Ps[wave][l16][16 + quad * 4] = __builtin_convertvector(sc[1], bf16x4);

        f32x4 av;
#pragma unroll
        for (int r = 0; r < 4; ++r) av[r] = __shfl(alpha, quad * 4 + r);

        bf16x8 pa = *(bf16x8*)&Ps[wave][l16][quad * 8];   // A-frag: row=q(l16), k=kv
#pragma unroll
        for (int n = 0; n < 4; ++n) {
            bf16x8 bv = *(bf16x8*)&Vt[n * 16 + l16][quad * 8];  // B-frag: col=d(l16), k=kv
            oacc[n] = __builtin_amdgcn_mfma_f32_16x16x32_bf16(pa, bv, oacc[n] * av, 0, 0, 0);
        }
    }

    float inv = 1.0f / lrun;
    f32x4 iv;
#pragma unroll
    for (int r = 0; r < 4; ++r) iv[r] = __shfl(inv, quad * 4 + r);
#pragma unroll
    for (int r = 0; r < 4; ++r) {
        long rowbase = (((long)b * S_ + qw + quad * 4 + r) * H_ + h) * HD_;
#pragma unroll
        for (int n = 0; n < 4; ++n)
            Ob[rowbase + n * 16 + l16] = (bf16_t)(oacc[n][r] * iv[r]);
    }
}

// ---------------- transpose + fp32->bf16 convert: W[Kd x Nd] -> Wt[Nd x Kd] ----------------
__global__ void tconv_kernel(const float* __restrict__ W, bf16_t* __restrict__ Wt,
                             int Kd, int Nd)
{
    __shared__ float t[32][33];
    int tx = threadIdx.x, ty = threadIdx.y;  // (32, 8)
    int bx = blockIdx.x, by = blockIdx.y;
#pragma unroll
    for (int i = 0; i < 4; ++i)
        t[ty + i * 8][tx] = W[(size_t)(by * 32 + ty + i * 8) * Nd + bx * 32 + tx];
    __syncthreads();
#pragma unroll
    for (int i = 0; i < 4; ++i)
        Wt[(size_t)(bx * 32 + ty + i * 8) * Kd + by * 32 + tx] = (bf16_t)t[tx][ty + i * 8];
}

// ---------------- bf16 MFMA GEMM: C[MxN] = A[MxK] * Bt[NxK]^T + bias ----------------
// BM=128, BN=64, BK=32, DOUBLE-BUFFERED: prefetch tile t+1 via global_load_lds
// while computing tile t; single barrier per K-step (T3-minimum 2-phase).
// LDS linear [row][32] with 4-slot XOR swizzle (pre-swizzled global source +
// swizzled ds_read; rule 21). grid.z = K-split; partial z -> Cf + z*pstride;
// bias only in split 0 (downstream ln sums partials).
__global__ __launch_bounds__(256) void gemm_bt_kernel(
    const bf16_t* __restrict__ A, const bf16_t* __restrict__ Bt,
    const float* __restrict__ bias, float* __restrict__ Cf,
    bf16_t* __restrict__ Cb, int M, int N, int K, int act, size_t pstride)
{
    __shared__ __align__(16) bf16_t As[2][128 * 32];   // 2 x 8 KB
    __shared__ __align__(16) bf16_t Bs[2][64 * 32];    // 2 x 4 KB
    int tid = threadIdx.x;
    int wave = tid >> 6, lane = tid & 63;
    int quad = lane >> 4, l16 = lane & 15;
    int m0 = blockIdx.x * 128;
    int n0 = blockIdx.y * 64;
    int Kc = K / gridDim.z;
    int kbeg = blockIdx.z * Kc;
    int kend = kbeg + Kc;
    float* Cfp = Cf ? Cf + (size_t)blockIdx.z * pstride : nullptr;

    int wm = (wave >> 1) * 64, wn = (wave & 1) * 32;

    // staging geometry: each wave-load covers 16 rows x 32 cols (1024 B);
    // lane -> row seg*16 + (lane>>2), linear slot lane&3; source col-slot XOR'd.
    int srow = lane >> 2;
    int sslot = (lane & 3) ^ (srow & 3);          // pre-swizzled global source slot
    // read-side swizzle: logical slot quad of row r lives at slot quad^(r&3); r&3 = l16&3
    int rslot = (quad ^ (l16 & 3)) * 8;

    f32x4 acc[4][2];
#pragma unroll
    for (int i = 0; i < 4; ++i)
#pragma unroll
        for (int j = 0; j < 2; ++j) acc[i][j] = (f32x4)0.f;

    const bf16_t* Ab = A + (size_t)(m0 + srow) * K + sslot * 8;
    const bf16_t* Bb = Bt + (size_t)(n0 + wave * 16 + srow) * K + sslot * 8;

    // prologue: stage first tile into buffer 0
    {
        int seg0 = wave * 2;
        gload16(Ab + (size_t)seg0 * 16 * K + kbeg, &As[0][seg0 * 512]);
        gload16(Ab + (size_t)(seg0 + 1) * 16 * K + kbeg, &As[0][(seg0 + 1) * 512]);
        gload16(Bb + kbeg, &Bs[0][wave * 512]);
    }
    __syncthreads();

    int cur = 0;
    for (int k0 = kbeg; k0 < kend; k0 += 32) {
        // prefetch next tile into cur^1 (loads complete under this tile's compute)
        int nxt = k0 + 32;
        if (nxt < kend) {
            int seg0 = wave * 2;
            gload16(Ab + (size_t)seg0 * 16 * K + nxt, &As[cur ^ 1][seg0 * 512]);
            gload16(Ab + (size_t)(seg0 + 1) * 16 * K + nxt, &As[cur ^ 1][(seg0 + 1) * 512]);
            gload16(Bb + nxt, &Bs[cur ^ 1][wave * 512]);
        }

        bf16x8 af[4], bfr[2];
#pragma unroll
        for (int i = 0; i < 4; ++i)
            af[i] = *(bf16x8*)&As[cur][(wm + i * 16 + l16) * 32 + rslot];
#pragma unroll
        for (int j = 0; j < 2; ++j)
            bfr[j] = *(bf16x8*)&Bs[cur][(wn + j * 16 + l16) * 32 + rslot];
#pragma unroll
        for (int i = 0; i < 4; ++i)
#pragma unroll
            for (int j = 0; j < 2; ++j)
                acc[i][j] = __builtin_amdgcn_mfma_f32_16x16x32_bf16(
                    af[i], bfr[j], acc[i][j], 0, 0, 0);

        __syncthreads();   // drains prefetch (vmcnt) + ds_reads (lgkm); one barrier/step
        cur ^= 1;
    }

#pragma unroll
    for (int j = 0; j < 2; ++j) {
        int col = n0 + wn + j * 16 + l16;
        float bv = (bias && blockIdx.z == 0) ? bias[col] : 0.f;
#pragma unroll
        for (int i = 0; i < 4; ++i) {
            int rbase = m0 + wm + i * 16 + quad * 4;
#pragma unroll
            for (int r = 0; r < 4; ++r) {
                float vv = acc[i][j][r] + bv;
                if (act == 1) vv = gelu_exact(vv);
                if (Cfp) Cfp[(size_t)(rbase + r) * N + col] = vv;
                if (Cb) Cb[(size_t)(rbase + r) * N + col] = (bf16_t)vv;
            }
        }
    }
}

// ---------------- fused (partial-sum) residual add + LayerNorm (row = one block) ----------------
__global__ __launch_bounds__(256) void ln_fused_kernel(
    const float* __restrict__ a0, const float* __restrict__ a1,
    const float* __restrict__ b,
    const float* __restrict__ w, const float* __restrict__ beta,
    float* __restrict__ out, bf16_t* __restrict__ outb)
{
    long row = blockIdx.x;
    int tid = threadIdx.x;
    f32x4 z = *(const f32x4*)&a0[row * D_ + tid * 4];
    if (a1) z += *(const f32x4*)&a1[row * D_ + tid * 4];
    if (b)  z += *(const f32x4*)&b[row * D_ + tid * 4];
    float s  = z[0] + z[1] + z[2] + z[3];
    float ss = z[0]*z[0] + z[1]*z[1] + z[2]*z[2] + z[3]*z[3];
#pragma unroll
    for (int off = 32; off >= 1; off >>= 1) {
        s  += __shfl_down(s, off);
        ss += __shfl_down(ss, off);
    }
    __shared__ float red[8];
    int lane = tid & 63, wid = tid >> 6;
    if (lane == 0) { red[wid * 2] = s; red[wid * 2 + 1] = ss; }
    __syncthreads();
    s  = red[0] + red[2] + red[4] + red[6];
    ss = red[1] + red[3] + red[5] + red[7];
    float mean = s * (1.0f / D_);
    float var  = ss * (1.0f / D_) - mean * mean;
    float rs = rsqrtf(var + 1e-5f);
    f32x4 wv = *(const f32x4*)&w[tid * 4];
    f32x4 bv = *(const f32x4*)&beta[tid * 4];
    f32x4 o = (z - mean) * rs * wv + bv;
    *(f32x4*)&out[row * D_ + tid * 4] = o;
    if (outb) *(bf16x4*)&outb[row * D_ + tid * 4] = __builtin_convertvector(o, bf16x4);
}

// ---------------- host launch ----------------
extern "C" void kernel_launch(void* const* d_in, const int* in_sizes, int n_in,
                              void* d_out, int out_size, void* d_ws, size_t ws_size,
                              hipStream_t stream)
{
    (void)in_sizes; (void)n_in; (void)out_size; (void)ws_size;
    const float* x    = (const float*)d_in[0];
    const float* pos  = (const float*)d_in[1];
    const float* Wq   = (const float*)d_in[2];
    const float* bq   = (const float*)d_in[3];
    const float* Wk   = (const float*)d_in[4];
    const float* bk   = (const float*)d_in[5];
    const float* Wv   = (const float*)d_in[6];
    const float* bv   = (const float*)d_in[7];
    const float* Wfc  = (const float*)d_in[8];
    const float* bfc  = (const float*)d_in[9];
    const float* ln1w = (const float*)d_in[10];
    const float* ln1b = (const float*)d_in[11];
    const float* ln2w = (const float*)d_in[12];
    const float* ln2b = (const float*)d_in[13];
    const float* W1   = (const float*)d_in[14];
    const float* b1   = (const float*)d_in[15];
    const float* W2   = (const float*)d_in[16];
    const float* b2   = (const float*)d_in[17];
    const float* lnfw = (const float*)d_in[18];
    const float* lnfb = (const float*)d_in[19];

    const size_t MB = 1 << 20;
    char* ws = (char*)d_ws;
    float*  y    = (float*)(ws);             //  0-8   fp32 activations
    bf16_t* yb   = (bf16_t*)(ws + 8 * MB);   //  8-12  bf16 activations
    bf16_t* qb   = (bf16_t*)(ws + 12 * MB);  // 12-16
    bf16_t* kb   = (bf16_t*)(ws + 16 * MB);  // 16-20
    bf16_t* vb   = (bf16_t*)(ws + 20 * MB);  // 20-24
    bf16_t* ob   = (bf16_t*)(ws + 24 * MB);  // 24-28
    float*  t1a  = (float*)(ws + 12 * MB);   // 12-20  Wfc partial 0 (qb/kb dead after attn)
    float*  t1b  = (float*)(ws + 28 * MB);   // 28-36  Wfc partial 1 (aliases 'add'; ln1 reduces in place)
    float*  t2a  = (float*)(ws + 12 * MB);   // 12-20  FFN2 partial 0
    float*  t2b  = (float*)(ws + 20 * MB);   // 20-28  FFN2 partial 1 (vb/ob dead by then)
    float*  add  = (float*)(ws + 28 * MB);   // 28-36
    bf16_t* addb = (bf16_t*)(ws + 36 * MB);  // 36-40
    bf16_t* vTb  = (bf16_t*)(ws + 40 * MB);  // 40-44  V^T [b,h,d,s] (ffb region, dead here)
    bf16_t* ffb  = (bf16_t*)(ws + 40 * MB);  // 40-56
    bf16_t* WT   = (bf16_t*)(ws + 56 * MB);  // 56-64  per-layer weight transpose

    const size_t pstride_wfc  = (size_t)16 * MB / sizeof(float); // t1b - t1a
    const size_t pstride_ffn2 = (size_t)8 * MB / sizeof(float);  // t2b - t2a

    add_pos_kernel<<<2048, 256, 0, stream>>>(x, pos, y, yb);

    for (int i = 0; i < NL_; ++i) {
        qkv_mfma_kernel<<<256, 256, 0, stream>>>(
            yb, Wq + i * 4096, bq + i * 64, Wk + i * 4096, bk + i * 64,
            Wv + i * 4096, bv + i * 64, qb, kb, vb);

        vtrans_kernel<<<dim3(32, 32), 256, 0, stream>>>(vb, vTb);

        attn_mfma_kernel<<<dim3(16, 32), 256, 0, stream>>>(qb, kb, vTb, ob);

        // ---- attention output projection: split-K=2, BN=64 -> 512 blocks ----
        tconv_kernel<<<dim3(32, 32), dim3(32, 8), 0, stream>>>(
            Wfc + (size_t)i * D_ * D_, WT, D_, D_);
        gemm_bt_kernel<<<dim3(16, 16, 2), 256, 0, stream>>>(
            ob, WT, bfc + i * D_, t1a, nullptr, 2048, D_, D_, 0, pstride_wfc);

        ln_fused_kernel<<<2048, 256, 0, stream>>>(
            t1a, t1b, y, ln1w + i * D_, ln1b + i * D_, add, addb);

        // ---- FFN1: BN=64 -> 1024 blocks (4 blocks/CU) ----
        tconv_kernel<<<dim3(128, 32), dim3(32, 8), 0, stream>>>(
            W1 + (size_t)i * D_ * DFF_, WT, D_, DFF_);
        gemm_bt_kernel<<<dim3(16, 64, 1), 256, 0, stream>>>(
            addb, WT, b1 + i * DFF_, nullptr, ffb, 2048, DFF_, D_, 1, 0);

        // ---- FFN2: split-K=2, BN=64 -> 512 blocks ----
        tconv_kernel<<<dim3(32, 128), dim3(32, 8), 0, stream>>>(
            W2 + (size_t)i * DFF_ * D_, WT, DFF_, D_);
        gemm_bt_kernel<<<dim3(16, 16, 2), 256, 0, stream>>>(
            ffb, WT, b2 + i * D_, t2a, nullptr, 2048, D_, DFF_, 0, pstride_ffn2);

        ln_fused_kernel<<<2048, 256, 0, stream>>>(
            t2a, t2b, add, ln2w + i * D_, ln2b + i * D_, y, yb);
    }

    ln_fused_kernel<<<2048, 256, 0, stream>>>(
        y, nullptr, nullptr, lnfw, lnfb, (float*)d_out, nullptr);
}

// Round 6
// 1242.227 us; speedup vs baseline: 1.4274x; 1.0209x over previous
//
#include <hip/hip_runtime.h>
#include <hip/hip_bf16.h>
#include <math.h>

#define B_   2
#define S_   1024
#define D_   1024
#define H_   16
#define HD_  64
#define NL_  6
#define DFF_ 4096

typedef __bf16 bf16_t;
typedef bf16_t bf16x8 __attribute__((ext_vector_type(8)));
typedef bf16_t bf16x4 __attribute__((ext_vector_type(4)));
typedef float  f32x4  __attribute__((ext_vector_type(4)));

__device__ __forceinline__ float gelu_exact(float x) {
    return 0.5f * x * (1.0f + erff(x * 0.70710678118654752f));
}

// async global->LDS, 16B per lane; LDS dest is wave-uniform base + lane*16
__device__ __forceinline__ void gload16(const bf16_t* g, bf16_t* l) {
    __builtin_amdgcn_global_load_lds(
        (const __attribute__((address_space(1))) void*)g,
        (__attribute__((address_space(3))) void*)l, 16, 0, 0);
}

// ---------------- y = x + pos (pos broadcast over batch); fp32 + bf16 out ----------------
__global__ __launch_bounds__(256) void add_pos_kernel(
    const float* __restrict__ x, const float* __restrict__ pos,
    float* __restrict__ y, bf16_t* __restrict__ yb)
{
    int idx = blockIdx.x * 256 + threadIdx.x;      // float4 index, [0, 524288)
    f32x4 xv = *(const f32x4*)&x[idx * 4];
    f32x4 pv = *(const f32x4*)&pos[(idx & 262143) * 4];  // S*D/4 = 262144
    f32x4 o = xv + pv;
    *(f32x4*)&y[idx * 4] = o;
    *(bf16x4*)&yb[idx * 4] = __builtin_convertvector(o, bf16x4);
}

// ---------------- QKV projection via MFMA ----------------
__global__ __launch_bounds__(256) void qkv_mfma_kernel(
    const bf16_t* __restrict__ yb,
    const float* __restrict__ Wq, const float* __restrict__ bq,
    const float* __restrict__ Wk, const float* __restrict__ bk,
    const float* __restrict__ Wv, const float* __restrict__ bv,
    bf16_t* __restrict__ q, bf16_t* __restrict__ k, bf16_t* __restrict__ v)
{
    __shared__ __align__(16) bf16_t As[128][72];
    __shared__ __align__(16) bf16_t Wt[3][64][72];   // W^T: [n][k], bf16

    int tid = threadIdx.x;
    long m0 = (long)blockIdx.x * 128;

#pragma unroll
    for (int it = 0; it < 4; ++it) {
        int c = it * 256 + tid;            // [0,1024) x8 elems
        int row = c >> 3, col = (c & 7) * 8;
        *(bf16x8*)&As[row][col] = *(const bf16x8*)&yb[(m0 + row) * 64 + col];
    }
#pragma unroll
    for (int it = 0; it < 16; ++it) {
        int i = it * 256 + tid;            // [0,4096)
        int r = i >> 6, c = i & 63;
        Wt[0][c][r] = (bf16_t)Wq[i];
        Wt[1][c][r] = (bf16_t)Wk[i];
        Wt[2][c][r] = (bf16_t)Wv[i];
    }
    __syncthreads();

    int wave = tid >> 6, lane = tid & 63;
    int quad = lane >> 4, l16 = lane & 15;
    int wm = wave * 32;

    bf16x8 a[2][2];
#pragma unroll
    for (int i = 0; i < 2; ++i)
#pragma unroll
        for (int ks = 0; ks < 2; ++ks)
            a[i][ks] = *(bf16x8*)&As[wm + i * 16 + l16][ks * 32 + quad * 8];

    f32x4 acc[3][2][4];
#pragma unroll
    for (int o = 0; o < 3; ++o)
#pragma unroll
        for (int i = 0; i < 2; ++i)
#pragma unroll
            for (int j = 0; j < 4; ++j) acc[o][i][j] = (f32x4)0.f;

#pragma unroll
    for (int o = 0; o < 3; ++o)
#pragma unroll
        for (int j = 0; j < 4; ++j) {
            bf16x8 b0 = *(bf16x8*)&Wt[o][j * 16 + l16][quad * 8];
            bf16x8 b1 = *(bf16x8*)&Wt[o][j * 16 + l16][32 + quad * 8];
#pragma unroll
            for (int i = 0; i < 2; ++i) {
                acc[o][i][j] = __builtin_amdgcn_mfma_f32_16x16x32_bf16(a[i][0], b0, acc[o][i][j], 0, 0, 0);
                acc[o][i][j] = __builtin_amdgcn_mfma_f32_16x16x32_bf16(a[i][1], b1, acc[o][i][j], 0, 0, 0);
            }
        }

    bf16_t* outs[3] = { q, k, v };
    const float* biases[3] = { bq, bk, bv };
#pragma unroll
    for (int o = 0; o < 3; ++o)
#pragma unroll
        for (int j = 0; j < 4; ++j) {
            int col = j * 16 + l16;
            float bias = biases[o][col];
#pragma unroll
            for (int i = 0; i < 2; ++i) {
                long rbase = m0 + wm + i * 16 + quad * 4;
#pragma unroll
                for (int r = 0; r < 4; ++r)
                    outs[o][(rbase + r) * 64 + col] = (bf16_t)(acc[o][i][j][r] + bias);
            }
        }
}

// ---------------- V transpose: vb [b,s,h,d] -> vT [b,h,d,s] ----------------
__global__ __launch_bounds__(256) void vtrans_kernel(
    const bf16_t* __restrict__ vb, bf16_t* __restrict__ vT)
{
    __shared__ __align__(16) bf16_t L[32][72];
    int tid = threadIdx.x;
    int s0 = blockIdx.x * 32;
    int bh = blockIdx.y;
    int b = bh >> 4, h = bh & 15;
    int sr = tid >> 3, dc = (tid & 7) * 8;
    *(bf16x8*)&L[sr][dc] =
        *(const bf16x8*)&vb[(((long)b * S_ + s0 + sr) * H_ + h) * HD_ + dc];
    __syncthreads();
    int dr = tid >> 2, sg = (tid & 3) * 8;
    bf16x8 o;
#pragma unroll
    for (int j = 0; j < 8; ++j) o[j] = L[sg + j][dr];
    *(bf16x8*)&vT[((long)bh * HD_ + dr) * S_ + s0 + sg] = o;
}

// ---------------- causal flash attention, swapped-QK bf16 MFMA, 64q x 32kv ----------------
__global__ __launch_bounds__(256) void attn_mfma_kernel(
    const bf16_t* __restrict__ Q, const bf16_t* __restrict__ K,
    const bf16_t* __restrict__ VT, bf16_t* __restrict__ Ob)
{
    __shared__ __align__(16) bf16_t Ks[32][72];       // [kv][d]
    __shared__ __align__(16) bf16_t Vt[64][40];       // [d][kv]
    __shared__ __align__(16) bf16_t Ps[4][16][40];    // per-wave P tile [q][kv]

    int tid = threadIdx.x;
    int wave = tid >> 6, lane = tid & 63;
    int quad = lane >> 4, l16 = lane & 15;
    int q0 = blockIdx.x * 64;
    int bh = blockIdx.y;
    int b = bh >> 4, h = bh & 15;
    int qw = q0 + wave * 16;
    const float scale = 0.125f;             // 1/sqrt(64)
    const float MASKED = -1.25e19f;         // -1e20 * scale, per reference order

    const bf16_t* Qbase = Q + (((long)b * S_ + qw + l16) * H_ + h) * HD_;
    bf16x8 aq0 = *(const bf16x8*)&Qbase[quad * 8];        // B-frag: col=q(l16), k=d
    bf16x8 aq1 = *(const bf16x8*)&Qbase[32 + quad * 8];

    float mrun = -3.0e38f, lrun = 0.f;      // state for q = qw + l16 (replicated over quads)
    f32x4 oacc[4];
#pragma unroll
    for (int n = 0; n < 4; ++n) oacc[n] = (f32x4)0.f;

    int srow = tid >> 3, scol = (tid & 7) * 8;   // K staging: 32 kv x 64 d
    int vdr = tid >> 2, vkg = (tid & 3) * 8;     // V^T staging: 64 d x 32 kv
    const bf16_t* VTbase = VT + ((long)bh * HD_ + vdr) * S_ + vkg;
    int qg = qw + l16;

    int nkt = (q0 + 64) / 32;
    for (int kt = 0; kt < nkt; ++kt) {
        int k0 = kt * 32;
        __syncthreads();
        *(bf16x8*)&Ks[srow][scol] =
            *(const bf16x8*)&K[(((long)b * S_ + k0 + srow) * H_ + h) * HD_ + scol];
        *(bf16x8*)&Vt[vdr][vkg] = *(const bf16x8*)&VTbase[k0];
        __syncthreads();

        if (k0 > qw + 15) continue;          // fully-masked tile for this wave

        f32x4 sc[2];
        sc[0] = (f32x4)0.f; sc[1] = (f32x4)0.f;
#pragma unroll
        for (int n = 0; n < 2; ++n) {
            bf16x8 ak0 = *(bf16x8*)&Ks[n * 16 + l16][quad * 8];       // A-frag: row=kv(l16), k=d
            bf16x8 ak1 = *(bf16x8*)&Ks[n * 16 + l16][32 + quad * 8];
            sc[n] = __builtin_amdgcn_mfma_f32_16x16x32_bf16(ak0, aq0, sc[n], 0, 0, 0);
            sc[n] = __builtin_amdgcn_mfma_f32_16x16x32_bf16(ak1, aq1, sc[n], 0, 0, 0);
        }
        float pmax = MASKED;
#pragma unroll
        for (int n = 0; n < 2; ++n)
#pragma unroll
            for (int r = 0; r < 4; ++r) {
                int kv = k0 + n * 16 + quad * 4 + r;
                float sv = (kv <= qg) ? sc[n][r] * scale : MASKED;
                sc[n][r] = sv;
                pmax = fmaxf(pmax, sv);
            }
        pmax = fmaxf(pmax, __shfl_xor(pmax, 16));
        pmax = fmaxf(pmax, __shfl_xor(pmax, 32));
        float mnew = fmaxf(mrun, pmax);
        float ls = 0.f;
#pragma unroll
        for (int n = 0; n < 2; ++n)
#pragma unroll
            for (int r = 0; r < 4; ++r) {
                float pv = __expf(sc[n][r] - mnew);
                sc[n][r] = pv;
                ls += pv;
            }
        ls += __shfl_xor(ls, 16);
        ls += __shfl_xor(ls, 32);
        float alpha = __expf(mrun - mnew);
        lrun = lrun * alpha + ls;
        mrun = mnew;

        *(bf16x4*)&Ps[wave][l16][quad * 4]      = __builtin_convertvector(sc[0], bf16x4);
        *(bf16x4*)&Ps[wave][l16][16 + quad * 4] = __builtin_convertvector(sc[1], bf16x4);

        f32x4 av;
#pragma unroll
        for (int r = 0; r < 4; ++r) av[r] = __shfl(alpha, quad * 4 + r);

        bf16x8 pa = *(bf16x8*)&Ps[wave][l16][quad * 8];   // A-frag: row=q(l16), k=kv
#pragma unroll
        for (int n = 0; n < 4; ++n) {
            bf16x8 bv = *(bf16x8*)&Vt[n * 16 + l16][quad * 8];  // B-frag: col=d(l16), k=kv
            oacc[n] = __builtin_amdgcn_mfma_f32_16x16x32_bf16(pa, bv, oacc[n] * av, 0, 0, 0);
        }
    }

    float inv = 1.0f / lrun;
    f32x4 iv;
#pragma unroll
    for (int r = 0; r < 4; ++r) iv[r] = __shfl(inv, quad * 4 + r);
#pragma unroll
    for (int r = 0; r < 4; ++r) {
        long rowbase = (((long)b * S_ + qw + quad * 4 + r) * H_ + h) * HD_;
#pragma unroll
        for (int n = 0; n < 4; ++n)
            Ob[rowbase + n * 16 + l16] = (bf16_t)(oacc[n][r] * iv[r]);
    }
}

// ---------------- transpose + fp32->bf16 convert: W[Kd x Nd] -> Wt[Nd x Kd] ----------------
__global__ void tconv_kernel(const float* __restrict__ W, bf16_t* __restrict__ Wt,
                             int Kd, int Nd)
{
    __shared__ float t[32][33];
    int tx = threadIdx.x, ty = threadIdx.y;  // (32, 8)
    int bx = blockIdx.x, by = blockIdx.y;
#pragma unroll
    for (int i = 0; i < 4; ++i)
        t[ty + i * 8][tx] = W[(size_t)(by * 32 + ty + i * 8) * Nd + bx * 32 + tx];
    __syncthreads();
#pragma unroll
    for (int i = 0; i < 4; ++i)
        Wt[(size_t)(bx * 32 + ty + i * 8) * Kd + by * 32 + tx] = (bf16_t)t[tx][ty + i * 8];
}

// ---------------- bf16 MFMA GEMM: C[MxN] = A[MxK] * Bt[NxK]^T + bias ----------------
// BM=128, BN=64, BK=32. 3-stage software pipeline with COUNTED vmcnt:
//   prologue stages tiles 0,1; iter t: s_waitcnt vmcnt(3) (tile t landed,
//   tile t+1 still in flight) -> raw s_barrier -> issue tile t+2 -> compute t.
// Never drains vmcnt to 0 in the main loop (T4); last tile peeled with vmcnt(0).
// LDS linear [row][32] with 4-slot XOR swizzle (pre-swizzled global source +
// swizzled ds_read). grid.z = K-split; partial z -> Cf + z*pstride.
__global__ __launch_bounds__(256) void gemm_bt_kernel(
    const bf16_t* __restrict__ A, const bf16_t* __restrict__ Bt,
    const float* __restrict__ bias, float* __restrict__ Cf,
    bf16_t* __restrict__ Cb, int M, int N, int K, int act, size_t pstride)
{
    __shared__ __align__(16) bf16_t As[3][128 * 32];   // 3 x 8 KB
    __shared__ __align__(16) bf16_t Bs[3][64 * 32];    // 3 x 4 KB
    int tid = threadIdx.x;
    int wave = tid >> 6, lane = tid & 63;
    int quad = lane >> 4, l16 = lane & 15;
    int m0 = blockIdx.x * 128;
    int n0 = blockIdx.y * 64;
    int Kc = K / gridDim.z;
    int kbeg = blockIdx.z * Kc;
    float* Cfp = Cf ? Cf + (size_t)blockIdx.z * pstride : nullptr;

    int wm = (wave >> 1) * 64, wn = (wave & 1) * 32;

    // staging geometry: each wave-load covers 16 rows x 32 cols (1024 B);
    // lane -> row seg*16 + (lane>>2), linear slot lane&3; source col-slot XOR'd.
    int srow = lane >> 2;
    int sslot = (lane & 3) ^ (srow & 3);          // pre-swizzled global source slot
    // read-side swizzle: logical slot quad of row r lives at slot quad^(r&3); r&3 = l16&3
    int rslot = (quad ^ (l16 & 3)) * 8;

    f32x4 acc[4][2];
#pragma unroll
    for (int i = 0; i < 4; ++i)
#pragma unroll
        for (int j = 0; j < 2; ++j) acc[i][j] = (f32x4)0.f;

    const bf16_t* Ab = A + (size_t)(m0 + srow) * K + sslot * 8;
    const bf16_t* Bb = Bt + (size_t)(n0 + wave * 16 + srow) * K + sslot * 8;
    int seg0 = wave * 2;
    int nt = Kc >> 5;                 // K tiles in this split (>= 16 for all call sites)

    // stage tile t into buffer buf: 3 gload_lds per wave (A: 2 segs, B: 1 seg)
    #define STAGE(t, buf) do {                                                      \
        int kk_ = kbeg + (t) * 32;                                                  \
        gload16(Ab + (size_t)seg0 * 16 * K + kk_, &As[(buf)][seg0 * 512]);          \
        gload16(Ab + (size_t)(seg0 + 1) * 16 * K + kk_, &As[(buf)][(seg0+1) * 512]);\
        gload16(Bb + kk_, &Bs[(buf)][wave * 512]);                                  \
    } while (0)

    #define COMPUTE(buf) do {                                                       \
        bf16x8 af[4], bfr[2];                                                       \
        _Pragma("unroll")                                                           \
        for (int i = 0; i < 4; ++i)                                                 \
            af[i] = *(bf16x8*)&As[(buf)][(wm + i * 16 + l16) * 32 + rslot];         \
        _Pragma("unroll")                                                           \
        for (int j = 0; j < 2; ++j)                                                 \
            bfr[j] = *(bf16x8*)&Bs[(buf)][(wn + j * 16 + l16) * 32 + rslot];        \
        _Pragma("unroll")                                                           \
        for (int i = 0; i < 4; ++i)                                                 \
            _Pragma("unroll")                                                       \
            for (int j = 0; j < 2; ++j)                                             \
                acc[i][j] = __builtin_amdgcn_mfma_f32_16x16x32_bf16(                \
                    af[i], bfr[j], acc[i][j], 0, 0, 0);                             \
    } while (0)

    STAGE(0, 0);
    STAGE(1, 1);

    int cur = 0, pf = 2;
    for (int t = 0; t < nt - 1; ++t) {
        // wait for tile t's 3 loads (tile t+1's 3 stay in flight), then sync
        asm volatile("s_waitcnt vmcnt(3)" ::: "memory");
        __builtin_amdgcn_s_barrier();
        __builtin_amdgcn_sched_barrier(0);
        if (t + 2 < nt) STAGE(t + 2, pf);
        COMPUTE(cur);
        cur = (cur == 2) ? 0 : cur + 1;
        pf  = (pf  == 2) ? 0 : pf  + 1;
    }
    // peeled last tile: drain everything
    asm volatile("s_waitcnt vmcnt(0)" ::: "memory");
    __builtin_amdgcn_s_barrier();
    __builtin_amdgcn_sched_barrier(0);
    COMPUTE(cur);

    #undef STAGE
    #undef COMPUTE

#pragma unroll
    for (int j = 0; j < 2; ++j) {
        int col = n0 + wn + j * 16 + l16;
        float bv = (bias && blockIdx.z == 0) ? bias[col] : 0.f;
#pragma unroll
        for (int i = 0; i < 4; ++i) {
            int rbase = m0 + wm + i * 16 + quad * 4;
#pragma unroll
            for (int r = 0; r < 4; ++r) {
                float vv = acc[i][j][r] + bv;
                if (act == 1) vv = gelu_exact(vv);
                if (Cfp) Cfp[(size_t)(rbase + r) * N + col] = vv;
                if (Cb) Cb[(size_t)(rbase + r) * N + col] = (bf16_t)vv;
            }
        }
    }
}

// ---------------- fused (partial-sum) residual add + LayerNorm (row = one block) ----------------
__global__ __launch_bounds__(256) void ln_fused_kernel(
    const float* __restrict__ a0, const float* __restrict__ a1,
    const float* __restrict__ b,
    const float* __restrict__ w, const float* __restrict__ beta,
    float* __restrict__ out, bf16_t* __restrict__ outb)
{
    long row = blockIdx.x;
    int tid = threadIdx.x;
    f32x4 z = *(const f32x4*)&a0[row * D_ + tid * 4];
    if (a1) z += *(const f32x4*)&a1[row * D_ + tid * 4];
    if (b)  z += *(const f32x4*)&b[row * D_ + tid * 4];
    float s  = z[0] + z[1] + z[2] + z[3];
    float ss = z[0]*z[0] + z[1]*z[1] + z[2]*z[2] + z[3]*z[3];
#pragma unroll
    for (int off = 32; off >= 1; off >>= 1) {
        s  += __shfl_down(s, off);
        ss += __shfl_down(ss, off);
    }
    __shared__ float red[8];
    int lane = tid & 63, wid = tid >> 6;
    if (lane == 0) { red[wid * 2] = s; red[wid * 2 + 1] = ss; }
    __syncthreads();
    s  = red[0] + red[2] + red[4] + red[6];
    ss = red[1] + red[3] + red[5] + red[7];
    float mean = s * (1.0f / D_);
    float var  = ss * (1.0f / D_) - mean * mean;
    float rs = rsqrtf(var + 1e-5f);
    f32x4 wv = *(const f32x4*)&w[tid * 4];
    f32x4 bv = *(const f32x4*)&beta[tid * 4];
    f32x4 o = (z - mean) * rs * wv + bv;
    *(f32x4*)&out[row * D_ + tid * 4] = o;
    if (outb) *(bf16x4*)&outb[row * D_ + tid * 4] = __builtin_convertvector(o, bf16x4);
}

// ---------------- host launch ----------------
extern "C" void kernel_launch(void* const* d_in, const int* in_sizes, int n_in,
                              void* d_out, int out_size, void* d_ws, size_t ws_size,
                              hipStream_t stream)
{
    (void)in_sizes; (void)n_in; (void)out_size; (void)ws_size;
    const float* x    = (const float*)d_in[0];
    const float* pos  = (const float*)d_in[1];
    const float* Wq   = (const float*)d_in[2];
    const float* bq   = (const float*)d_in[3];
    const float* Wk   = (const float*)d_in[4];
    const float* bk   = (const float*)d_in[5];
    const float* Wv   = (const float*)d_in[6];
    const float* bv   = (const float*)d_in[7];
    const float* Wfc  = (const float*)d_in[8];
    const float* bfc  = (const float*)d_in[9];
    const float* ln1w = (const float*)d_in[10];
    const float* ln1b = (const float*)d_in[11];
    const float* ln2w = (const float*)d_in[12];
    const float* ln2b = (const float*)d_in[13];
    const float* W1   = (const float*)d_in[14];
    const float* b1   = (const float*)d_in[15];
    const float* W2   = (const float*)d_in[16];
    const float* b2   = (const float*)d_in[17];
    const float* lnfw = (const float*)d_in[18];
    const float* lnfb = (const float*)d_in[19];

    const size_t MB = 1 << 20;
    char* ws = (char*)d_ws;
    float*  y    = (float*)(ws);             //  0-8   fp32 activations
    bf16_t* yb   = (bf16_t*)(ws + 8 * MB);   //  8-12  bf16 activations
    bf16_t* qb   = (bf16_t*)(ws + 12 * MB);  // 12-16
    bf16_t* kb   = (bf16_t*)(ws + 16 * MB);  // 16-20
    bf16_t* vb   = (bf16_t*)(ws + 20 * MB);  // 20-24
    bf16_t* ob   = (bf16_t*)(ws + 24 * MB);  // 24-28
    float*  t1a  = (float*)(ws + 12 * MB);   // 12-20  Wfc partial 0 (qb/kb dead after attn)
    float*  t1b  = (float*)(ws + 28 * MB);   // 28-36  Wfc partial 1 (aliases 'add'; ln1 reduces in place)
    float*  t2a  = (float*)(ws + 12 * MB);   // 12-20  FFN2 partial 0
    float*  t2b  = (float*)(ws + 20 * MB);   // 20-28  FFN2 partial 1 (vb/ob dead by then)
    float*  add  = (float*)(ws + 28 * MB);   // 28-36
    bf16_t* addb = (bf16_t*)(ws + 36 * MB);  // 36-40
    bf16_t* vTb  = (bf16_t*)(ws + 40 * MB);  // 40-44  V^T [b,h,d,s] (ffb region, dead here)
    bf16_t* ffb  = (bf16_t*)(ws + 40 * MB);  // 40-56
    bf16_t* WT   = (bf16_t*)(ws + 56 * MB);  // 56-64  per-layer weight transpose

    const size_t pstride_wfc  = (size_t)16 * MB / sizeof(float); // t1b - t1a
    const size_t pstride_ffn2 = (size_t)8 * MB / sizeof(float);  // t2b - t2a

    add_pos_kernel<<<2048, 256, 0, stream>>>(x, pos, y, yb);

    for (int i = 0; i < NL_; ++i) {
        qkv_mfma_kernel<<<256, 256, 0, stream>>>(
            yb, Wq + i * 4096, bq + i * 64, Wk + i * 4096, bk + i * 64,
            Wv + i * 4096, bv + i * 64, qb, kb, vb);

        vtrans_kernel<<<dim3(32, 32), 256, 0, stream>>>(vb, vTb);

        attn_mfma_kernel<<<dim3(16, 32), 256, 0, stream>>>(qb, kb, vTb, ob);

        // ---- attention output projection: split-K=2, BN=64 -> 512 blocks ----
        tconv_kernel<<<dim3(32, 32), dim3(32, 8), 0, stream>>>(
            Wfc + (size_t)i * D_ * D_, WT, D_, D_);
        gemm_bt_kernel<<<dim3(16, 16, 2), 256, 0, stream>>>(
            ob, WT, bfc + i * D_, t1a, nullptr, 2048, D_, D_, 0, pstride_wfc);

        ln_fused_kernel<<<2048, 256, 0, stream>>>(
            t1a, t1b, y, ln1w + i * D_, ln1b + i * D_, add, addb);

        // ---- FFN1: BN=64 -> 1024 blocks (4 blocks/CU) ----
        tconv_kernel<<<dim3(128, 32), dim3(32, 8), 0, stream>>>(
            W1 + (size_t)i * D_ * DFF_, WT, D_, DFF_);
        gemm_bt_kernel<<<dim3(16, 64, 1), 256, 0, stream>>>(
            addb, WT, b1 + i * DFF_, nullptr, ffb, 2048, DFF_, D_, 1, 0);

        // ---- FFN2: split-K=2, BN=64 -> 512 blocks ----
        tconv_kernel<<<dim3(32, 128), dim3(32, 8), 0, stream>>>(
            W2 + (size_t)i * DFF_ * D_, WT, DFF_, D_);
        gemm_bt_kernel<<<dim3(16, 16, 2), 256, 0, stream>>>(
            ffb, WT, b2 + i * D_, t2a, nullptr, 2048, D_, DFF_, 0, pstride_ffn2);

        ln_fused_kernel<<<2048, 256, 0, stream>>>(
            t2a, t2b, add, ln2w + i * D_, ln2b + i * D_, y, yb);
    }

    ln_fused_kernel<<<2048, 256, 0, stream>>>(
        y, nullptr, nullptr, lnfw, lnfb, (float*)d_out, nullptr);
}